// Round 2
// baseline (426.796 us; speedup 1.0000x reference)
//
#include <hip/hip_runtime.h>
#include <math.h>

#define N_TOK 4096
#define DMODEL 512
#define NHEAD 8
#define DHEAD 64
#define CTX 10
#define NROW 8192  // B * N_TOK

// ---------------------------------------------------------------------------
// Stage 1: fused Q/V projection GEMM.
// X[B*N, D] @ [Wq | Wv] -> Qt, Vt stored DIM-MAJOR as [B*H, 64, N]
// so that stage-2 loads are lane-coalesced along tokens.
// Tile: 128x128x8, 256 threads, 8x8 micro-tile in split-4 layout.
// ---------------------------------------------------------------------------
__global__ __launch_bounds__(256) void gemm_qv(
    const float* __restrict__ x,
    const float* __restrict__ Wq,
    const float* __restrict__ Wv,
    float* __restrict__ Qt,
    float* __restrict__ Vt)
{
    constexpr int BM = 128, BN = 128, BK = 8;
    __shared__ float As[BK][BM];   // transposed A tile: As[k][m]
    __shared__ float Bs[BK][BN];

    const int tid  = threadIdx.x;
    const int row0 = blockIdx.y * BM;           // over B*N = 8192
    const int col0 = blockIdx.x * BN;           // over 1024 fused cols
    const bool isQ = (col0 < 512);
    const float* W = isQ ? Wq : Wv;
    const int wcol0 = col0 & 511;

    const int a_r = tid >> 1;          // 0..127
    const int a_c = (tid & 1) * 4;     // 0 or 4
    const int b_r = tid >> 5;          // 0..7
    const int b_c = (tid & 31) * 4;    // 0..124

    const int ty = tid >> 4;           // 0..15
    const int tx = tid & 15;           // 0..15

    float acc[8][8];
#pragma unroll
    for (int i = 0; i < 8; i++)
#pragma unroll
        for (int j = 0; j < 8; j++) acc[i][j] = 0.f;

    for (int k0 = 0; k0 < DMODEL; k0 += BK) {
        const float4 av = *(const float4*)(x + (size_t)(row0 + a_r) * DMODEL + k0 + a_c);
        const int cg = wcol0 + b_c;            // global col in [0,512)
        const int h  = cg >> 6;
        const int kk = cg & 63;
        const float4 bv = *(const float4*)(W + ((size_t)h * DMODEL + (k0 + b_r)) * DHEAD + kk);

        __syncthreads();
        As[a_c + 0][a_r] = av.x;
        As[a_c + 1][a_r] = av.y;
        As[a_c + 2][a_r] = av.z;
        As[a_c + 3][a_r] = av.w;
        *(float4*)&Bs[b_r][b_c] = bv;
        __syncthreads();

#pragma unroll
        for (int k = 0; k < BK; k++) {
            float a[8], b[8];
            *(float4*)(a)     = *(const float4*)&As[k][ty * 4];
            *(float4*)(a + 4) = *(const float4*)&As[k][ty * 4 + 64];
            *(float4*)(b)     = *(const float4*)&Bs[k][tx * 4];
            *(float4*)(b + 4) = *(const float4*)&Bs[k][tx * 4 + 64];
#pragma unroll
            for (int i = 0; i < 8; i++)
#pragma unroll
                for (int j = 0; j < 8; j++) acc[i][j] += a[i] * b[j];
        }
    }

    // Epilogue: write dim-major [bh, kk, n]. acc row i = ig*4+ii <-> token
    // row0+ig*64+ty*4+ii (ii consecutive -> float4 along tokens).
    float* outBase = isQ ? Qt : Vt;
#pragma unroll
    for (int jg = 0; jg < 2; jg++) {
#pragma unroll
        for (int jj = 0; jj < 4; jj++) {
            const int c  = wcol0 + tx * 4 + jg * 64 + jj;
            const int h  = c >> 6;
            const int kk = c & 63;
#pragma unroll
            for (int ig = 0; ig < 2; ig++) {
                const int r0 = row0 + ig * 64 + ty * 4;
                const int bb = r0 >> 12;
                const int n  = r0 & (N_TOK - 1);
                float4 v;
                v.x = acc[ig * 4 + 0][jg * 4 + jj];
                v.y = acc[ig * 4 + 1][jg * 4 + jj];
                v.z = acc[ig * 4 + 2][jg * 4 + jj];
                v.w = acc[ig * 4 + 3][jg * 4 + jj];
                *(float4*)(outBase + (((size_t)(bb * NHEAD + h) * DHEAD + kk) * N_TOK + n)) = v;
            }
        }
    }
}

// ---------------------------------------------------------------------------
// Stage 2: banded attention, dim-major. 2 threads per (b,h,i): lane&31 = token
// within a 32-row group, (tid>>5)&1 = which 32-dim half. Score halves are
// combined with one shfl_xor(32). All loads/stores lane-coalesced.
// No max-subtraction: scores are O(1e-5), exp(s)/sum(exp(s)) is exact here;
// masked / out-of-range taps get weight 0 (identical to exp(-1e9) underflow).
// Output written dim-major heads layout Ht[h*64+k][b*4096+i].
// ---------------------------------------------------------------------------
__global__ __launch_bounds__(256) void attn_band(
    const float* __restrict__ Qt,
    const float* __restrict__ Vt,
    float* __restrict__ Ht)
{
    const int tid  = threadIdx.x;
    const int bh   = blockIdx.x >> 5;          // 0..15
    const int tile = blockIdx.x & 31;          // 0..31 (128 tokens per tile)
    const int wv   = tid >> 6;                 // 0..3
    const int p    = (tid >> 5) & 1;           // dim half
    const int i    = tile * 128 + wv * 32 + (tid & 31);
    const int b    = bh >> 3;
    const int h    = bh & 7;

    const float* qbase = Qt + ((size_t)bh * DHEAD + p * 32) * N_TOK;
    const float* vbase = Vt + ((size_t)bh * DHEAD + p * 32) * N_TOK;

    float q[32];
#pragma unroll
    for (int k = 0; k < 32; k++) q[k] = qbase[(size_t)k * N_TOK + i];

    float c[32];
#pragma unroll
    for (int k = 0; k < 32; k++) c[k] = 0.f;

    float Z = 0.f;
    float vbuf[2][32];

    {   // preload d = 0 (j = i - CTX, clamped)
        const int j0 = min(max(i - CTX, 0), N_TOK - 1);
#pragma unroll
        for (int k = 0; k < 32; k++) vbuf[0][k] = vbase[(size_t)k * N_TOK + j0];
    }

#pragma unroll
    for (int d = 0; d < 2 * CTX + 1; d++) {
        if (d < 2 * CTX) {   // prefetch next tap (double buffer)
            const int jn = min(max(i + d + 1 - CTX, 0), N_TOK - 1);
#pragma unroll
            for (int k = 0; k < 32; k++) vbuf[(d + 1) & 1][k] = vbase[(size_t)k * N_TOK + jn];
        }
        const float* v = vbuf[d & 1];
        float s = 0.f;
#pragma unroll
        for (int k = 0; k < 32; k++) s += q[k] * v[k];
        s += __shfl_xor(s, 32, 64);            // combine the two dim-halves

        const int j = i + d - CTX;
        const bool valid = (d != CTX) && (j >= 0) && (j < N_TOK);
        const float w = valid ? __expf(s * 0.0625f) : 0.f;
        Z += w;
#pragma unroll
        for (int k = 0; k < 32; k++) c[k] += w * v[k];
    }

    const float inv = 1.f / Z;
    float* obase = Ht + ((size_t)(h * DHEAD + p * 32)) * NROW + (size_t)b * N_TOK + i;
#pragma unroll
    for (int k = 0; k < 32; k++) obase[(size_t)k * NROW] = c[k] * inv;
}

// ---------------------------------------------------------------------------
// Stage 3: output projection. heads^T[512, 8192] @ -> out[8192, 512].
// A arrives dim-major (exactly the As[k][m] LDS layout): the A-tile load is a
// straight coalesced float4 copy, no transpose needed.
// ---------------------------------------------------------------------------
__global__ __launch_bounds__(256) void gemm_out(
    const float* __restrict__ At,    // heads^T [512, 8192]
    const float* __restrict__ Bw,    // Wup [512, 512]
    float* __restrict__ out)         // [8192, 512]
{
    constexpr int BM = 128, BN = 128, BK = 8;
    __shared__ float As[BK][BM];
    __shared__ float Bs[BK][BN];

    const int tid  = threadIdx.x;
    const int row0 = blockIdx.y * BM;
    const int col0 = blockIdx.x * BN;

    const int a_kr = tid >> 5;         // 0..7
    const int a_m4 = (tid & 31) * 4;   // 0..124
    const int b_r  = tid >> 5;
    const int b_c  = (tid & 31) * 4;

    const int ty = tid >> 4;
    const int tx = tid & 15;

    float acc[8][8];
#pragma unroll
    for (int i = 0; i < 8; i++)
#pragma unroll
        for (int j = 0; j < 8; j++) acc[i][j] = 0.f;

    for (int k0 = 0; k0 < DMODEL; k0 += BK) {
        const float4 av = *(const float4*)(At + (size_t)(k0 + a_kr) * NROW + row0 + a_m4);
        const float4 bv = *(const float4*)(Bw + (size_t)(k0 + b_r) * DMODEL + col0 + b_c);

        __syncthreads();
        *(float4*)&As[a_kr][a_m4] = av;
        *(float4*)&Bs[b_r][b_c] = bv;
        __syncthreads();

#pragma unroll
        for (int k = 0; k < BK; k++) {
            float a[8], b[8];
            *(float4*)(a)     = *(const float4*)&As[k][ty * 4];
            *(float4*)(a + 4) = *(const float4*)&As[k][ty * 4 + 64];
            *(float4*)(b)     = *(const float4*)&Bs[k][tx * 4];
            *(float4*)(b + 4) = *(const float4*)&Bs[k][tx * 4 + 64];
#pragma unroll
            for (int i = 0; i < 8; i++)
#pragma unroll
                for (int j = 0; j < 8; j++) acc[i][j] += a[i] * b[j];
        }
    }

#pragma unroll
    for (int ig = 0; ig < 2; ig++) {
#pragma unroll
        for (int ii = 0; ii < 4; ii++) {
            const int r = row0 + ig * 64 + ty * 4 + ii;
#pragma unroll
            for (int jg = 0; jg < 2; jg++) {
                const int col = col0 + tx * 4 + jg * 64;
                float4 v;
                v.x = acc[ig * 4 + ii][jg * 4 + 0];
                v.y = acc[ig * 4 + ii][jg * 4 + 1];
                v.z = acc[ig * 4 + ii][jg * 4 + 2];
                v.w = acc[ig * 4 + ii][jg * 4 + 3];
                *(float4*)(out + (size_t)r * DMODEL + col) = v;
            }
        }
    }
}

// ---------------------------------------------------------------------------
extern "C" void kernel_launch(void* const* d_in, const int* in_sizes, int n_in,
                              void* d_out, int out_size, void* d_ws, size_t ws_size,
                              hipStream_t stream)
{
    const float* x   = (const float*)d_in[0];   // [2, 4096, 512]
    const float* Wq  = (const float*)d_in[1];   // [8, 512, 64]
    const float* Wv  = (const float*)d_in[2];   // [8, 512, 64]
    const float* Wup = (const float*)d_in[3];   // [512, 512]
    float* out = (float*)d_out;                 // [2, 4096, 512]

    const size_t QV = (size_t)2 * NHEAD * N_TOK * DHEAD;  // 4,194,304 floats
    float* Qt = (float*)d_ws;
    float* Vt = Qt + QV;
    float* Ht = Vt + QV;

    dim3 blk(256);
    // Stage 1: [8192x512] @ [512x1024] fused Q|V, dim-major outputs
    gemm_qv<<<dim3(8, 64), blk, 0, stream>>>(x, Wq, Wv, Qt, Vt);
    // Stage 2: banded softmax-attention, 2 threads per (b,h,i)
    attn_band<<<dim3(512), blk, 0, stream>>>(Qt, Vt, Ht);
    // Stage 3: heads^T [512x8192] -> out [8192x512]
    gemm_out<<<dim3(4, 64), blk, 0, stream>>>(Ht, Wup, out);
}

// Round 3
// 283.512 us; speedup vs baseline: 1.5054x; 1.5054x over previous
//
#include <hip/hip_runtime.h>
#include <math.h>

#define N_TOK 4096
#define DMODEL 512
#define NHEAD 8
#define DHEAD 64
#define CTX 10
#define NROW 8192  // B * N_TOK

// ---------------------------------------------------------------------------
// Stage 1: fused Q/V projection GEMM.
// X[B*N, D] @ [Wq | Wv] -> Qt, Vt stored DIM-MAJOR as [B*H, 64, N]
// so that stage-2 loads are lane-coalesced along tokens.
// Tile: 128x128x8, 256 threads, 8x8 micro-tile in split-4 layout.
// ---------------------------------------------------------------------------
__global__ __launch_bounds__(256) void gemm_qv(
    const float* __restrict__ x,
    const float* __restrict__ Wq,
    const float* __restrict__ Wv,
    float* __restrict__ Qt,
    float* __restrict__ Vt)
{
    constexpr int BM = 128, BN = 128, BK = 8;
    __shared__ float As[BK][BM];   // transposed A tile: As[k][m]
    __shared__ float Bs[BK][BN];

    const int tid  = threadIdx.x;
    const int row0 = blockIdx.y * BM;           // over B*N = 8192
    const int col0 = blockIdx.x * BN;           // over 1024 fused cols
    const bool isQ = (col0 < 512);
    const float* W = isQ ? Wq : Wv;
    const int wcol0 = col0 & 511;

    const int a_r = tid >> 1;          // 0..127
    const int a_c = (tid & 1) * 4;     // 0 or 4
    const int b_r = tid >> 5;          // 0..7
    const int b_c = (tid & 31) * 4;    // 0..124

    const int ty = tid >> 4;           // 0..15
    const int tx = tid & 15;           // 0..15

    float acc[8][8];
#pragma unroll
    for (int i = 0; i < 8; i++)
#pragma unroll
        for (int j = 0; j < 8; j++) acc[i][j] = 0.f;

    for (int k0 = 0; k0 < DMODEL; k0 += BK) {
        const float4 av = *(const float4*)(x + (size_t)(row0 + a_r) * DMODEL + k0 + a_c);
        const int cg = wcol0 + b_c;            // global col in [0,512)
        const int h  = cg >> 6;
        const int kk = cg & 63;
        const float4 bv = *(const float4*)(W + ((size_t)h * DMODEL + (k0 + b_r)) * DHEAD + kk);

        __syncthreads();
        As[a_c + 0][a_r] = av.x;
        As[a_c + 1][a_r] = av.y;
        As[a_c + 2][a_r] = av.z;
        As[a_c + 3][a_r] = av.w;
        *(float4*)&Bs[b_r][b_c] = bv;
        __syncthreads();

#pragma unroll
        for (int k = 0; k < BK; k++) {
            float a[8], b[8];
            *(float4*)(a)     = *(const float4*)&As[k][ty * 4];
            *(float4*)(a + 4) = *(const float4*)&As[k][ty * 4 + 64];
            *(float4*)(b)     = *(const float4*)&Bs[k][tx * 4];
            *(float4*)(b + 4) = *(const float4*)&Bs[k][tx * 4 + 64];
#pragma unroll
            for (int i = 0; i < 8; i++)
#pragma unroll
                for (int j = 0; j < 8; j++) acc[i][j] += a[i] * b[j];
        }
    }

    // Epilogue: write dim-major [bh, kk, n].
    float* outBase = isQ ? Qt : Vt;
#pragma unroll
    for (int jg = 0; jg < 2; jg++) {
#pragma unroll
        for (int jj = 0; jj < 4; jj++) {
            const int c  = wcol0 + tx * 4 + jg * 64 + jj;
            const int h  = c >> 6;
            const int kk = c & 63;
#pragma unroll
            for (int ig = 0; ig < 2; ig++) {
                const int r0 = row0 + ig * 64 + ty * 4;
                const int bb = r0 >> 12;
                const int n  = r0 & (N_TOK - 1);
                float4 v;
                v.x = acc[ig * 4 + 0][jg * 4 + jj];
                v.y = acc[ig * 4 + 1][jg * 4 + jj];
                v.z = acc[ig * 4 + 2][jg * 4 + jj];
                v.w = acc[ig * 4 + 3][jg * 4 + jj];
                *(float4*)(outBase + (((size_t)(bb * NHEAD + h) * DHEAD + kk) * N_TOK + n)) = v;
            }
        }
    }
}

// ---------------------------------------------------------------------------
// Stage 2: banded attention, dim-major, 4 threads per token (16 dims each).
// Lane map: token = tile*64 + wv*16 + (lane&15), dim quarter p = lane>>4.
// Per-thread state: q[16] + c[16] + vbuf[2][16] = 64 floats -> no spill
// (round 2 used 128 floats/thread -> VGPR=256 + 211MB scratch writes).
// Score combined across quarters with shfl_xor(16) + shfl_xor(32).
// No max-subtraction: scores are O(1e-4), exp(s)/sum(exp(s)) is exact here;
// masked / out-of-range taps get weight 0 (identical to exp(-1e9) underflow).
// ---------------------------------------------------------------------------
__global__ __launch_bounds__(256) void attn_band(
    const float* __restrict__ Qt,
    const float* __restrict__ Vt,
    float* __restrict__ Ht)
{
    const int tid  = threadIdx.x;
    const int bh   = blockIdx.x >> 6;          // 0..15
    const int tile = blockIdx.x & 63;          // 0..63 (64 tokens per block)
    const int wv   = tid >> 6;                 // 0..3 (wave -> token subgroup)
    const int lane = tid & 63;
    const int p    = lane >> 4;                // dim quarter 0..3
    const int il   = lane & 15;
    const int i    = tile * 64 + wv * 16 + il; // token
    const int b    = bh >> 3;
    const int h    = bh & 7;

    const float* qbase = Qt + ((size_t)bh * DHEAD + p * 16) * N_TOK;
    const float* vbase = Vt + ((size_t)bh * DHEAD + p * 16) * N_TOK;

    float q[16];
#pragma unroll
    for (int k = 0; k < 16; k++) q[k] = qbase[(size_t)k * N_TOK + i];

    float c[16];
#pragma unroll
    for (int k = 0; k < 16; k++) c[k] = 0.f;

    float Z = 0.f;
    float vbuf[2][16];

    {   // preload d = 0 tap (j = i - CTX, clamped)
        const int j0 = min(max(i - CTX, 0), N_TOK - 1);
#pragma unroll
        for (int k = 0; k < 16; k++) vbuf[0][k] = vbase[(size_t)k * N_TOK + j0];
    }

#pragma unroll
    for (int d = 0; d < 2 * CTX + 1; d++) {
        if (d < 2 * CTX) {   // prefetch next tap (double buffer)
            const int jn = min(max(i + d + 1 - CTX, 0), N_TOK - 1);
#pragma unroll
            for (int k = 0; k < 16; k++) vbuf[(d + 1) & 1][k] = vbase[(size_t)k * N_TOK + jn];
        }
        const float* v = vbuf[d & 1];
        float s = 0.f;
#pragma unroll
        for (int k = 0; k < 16; k++) s += q[k] * v[k];
        s += __shfl_xor(s, 16, 64);            // combine quarters 0<->1, 2<->3
        s += __shfl_xor(s, 32, 64);            // combine halves

        const int j = i + d - CTX;
        const bool valid = (d != CTX) && (j >= 0) && (j < N_TOK);
        const float w = valid ? __expf(s * 0.0625f) : 0.f;
        Z += w;
#pragma unroll
        for (int k = 0; k < 16; k++) c[k] += w * v[k];
    }

    const float inv = 1.f / Z;
    float* obase = Ht + ((size_t)(h * DHEAD + p * 16)) * NROW + (size_t)b * N_TOK + i;
#pragma unroll
    for (int k = 0; k < 16; k++) obase[(size_t)k * NROW] = c[k] * inv;
}

// ---------------------------------------------------------------------------
// Stage 3: output projection. heads^T[512, 8192] @ Wup[512,512] -> out[8192, 512].
// A arrives dim-major (exactly the As[k][m] LDS layout): the A-tile load is a
// straight coalesced float4 copy, no transpose needed.
// ---------------------------------------------------------------------------
__global__ __launch_bounds__(256) void gemm_out(
    const float* __restrict__ At,    // heads^T [512, 8192]
    const float* __restrict__ Bw,    // Wup [512, 512]
    float* __restrict__ out)         // [8192, 512]
{
    constexpr int BM = 128, BN = 128, BK = 8;
    __shared__ float As[BK][BM];
    __shared__ float Bs[BK][BN];

    const int tid  = threadIdx.x;
    const int row0 = blockIdx.y * BM;
    const int col0 = blockIdx.x * BN;

    const int a_kr = tid >> 5;         // 0..7
    const int a_m4 = (tid & 31) * 4;   // 0..124
    const int b_r  = tid >> 5;
    const int b_c  = (tid & 31) * 4;

    const int ty = tid >> 4;
    const int tx = tid & 15;

    float acc[8][8];
#pragma unroll
    for (int i = 0; i < 8; i++)
#pragma unroll
        for (int j = 0; j < 8; j++) acc[i][j] = 0.f;

    for (int k0 = 0; k0 < DMODEL; k0 += BK) {
        const float4 av = *(const float4*)(At + (size_t)(k0 + a_kr) * NROW + row0 + a_m4);
        const float4 bv = *(const float4*)(Bw + (size_t)(k0 + b_r) * DMODEL + col0 + b_c);

        __syncthreads();
        *(float4*)&As[a_kr][a_m4] = av;
        *(float4*)&Bs[b_r][b_c] = bv;
        __syncthreads();

#pragma unroll
        for (int k = 0; k < BK; k++) {
            float a[8], b[8];
            *(float4*)(a)     = *(const float4*)&As[k][ty * 4];
            *(float4*)(a + 4) = *(const float4*)&As[k][ty * 4 + 64];
            *(float4*)(b)     = *(const float4*)&Bs[k][tx * 4];
            *(float4*)(b + 4) = *(const float4*)&Bs[k][tx * 4 + 64];
#pragma unroll
            for (int i = 0; i < 8; i++)
#pragma unroll
                for (int j = 0; j < 8; j++) acc[i][j] += a[i] * b[j];
        }
    }

#pragma unroll
    for (int ig = 0; ig < 2; ig++) {
#pragma unroll
        for (int ii = 0; ii < 4; ii++) {
            const int r = row0 + ig * 64 + ty * 4 + ii;
#pragma unroll
            for (int jg = 0; jg < 2; jg++) {
                const int col = col0 + tx * 4 + jg * 64;
                float4 v;
                v.x = acc[ig * 4 + ii][jg * 4 + 0];
                v.y = acc[ig * 4 + ii][jg * 4 + 1];
                v.z = acc[ig * 4 + ii][jg * 4 + 2];
                v.w = acc[ig * 4 + ii][jg * 4 + 3];
                *(float4*)(out + (size_t)r * DMODEL + col) = v;
            }
        }
    }
}

// ---------------------------------------------------------------------------
extern "C" void kernel_launch(void* const* d_in, const int* in_sizes, int n_in,
                              void* d_out, int out_size, void* d_ws, size_t ws_size,
                              hipStream_t stream)
{
    const float* x   = (const float*)d_in[0];   // [2, 4096, 512]
    const float* Wq  = (const float*)d_in[1];   // [8, 512, 64]
    const float* Wv  = (const float*)d_in[2];   // [8, 512, 64]
    const float* Wup = (const float*)d_in[3];   // [512, 512]
    float* out = (float*)d_out;                 // [2, 4096, 512]

    const size_t QV = (size_t)2 * NHEAD * N_TOK * DHEAD;  // 4,194,304 floats
    float* Qt = (float*)d_ws;
    float* Vt = Qt + QV;
    float* Ht = Vt + QV;

    dim3 blk(256);
    // Stage 1: [8192x512] @ [512x1024] fused Q|V, dim-major outputs
    gemm_qv<<<dim3(8, 64), blk, 0, stream>>>(x, Wq, Wv, Qt, Vt);
    // Stage 2: banded softmax-attention, 4 threads per (b,h,i)
    attn_band<<<dim3(1024), blk, 0, stream>>>(Qt, Vt, Ht);
    // Stage 3: heads^T [512x8192] -> out [8192x512]
    gemm_out<<<dim3(4, 64), blk, 0, stream>>>(Ht, Wup, out);
}

// Round 4
// 158.165 us; speedup vs baseline: 2.6984x; 1.7925x over previous
//
#include <hip/hip_runtime.h>
#include <math.h>

#define N_TOK 4096
#define DMODEL 512
#define NHEAD 8
#define DHEAD 64
#define CTX 10
#define NROW 8192  // B * N_TOK

typedef __bf16 bf16x8 __attribute__((ext_vector_type(8)));
typedef float  f32x4  __attribute__((ext_vector_type(4)));

#define GLOAD_LDS16(g, l) __builtin_amdgcn_global_load_lds(                 \
    (const __attribute__((address_space(1))) void*)(g),                     \
    (__attribute__((address_space(3))) void*)(l), 16, 0, 0)

// ---------------------------------------------------------------------------
// Convert x (fp32 row-major [8192][512]) -> bf16 same layout.
// ---------------------------------------------------------------------------
__global__ __launch_bounds__(256) void conv_x(const float* __restrict__ x,
                                              __bf16* __restrict__ xb)
{
    const int idx = (blockIdx.x * 256 + threadIdx.x) * 8;
    const float4 a = *(const float4*)(x + idx);
    const float4 b = *(const float4*)(x + idx + 4);
    bf16x8 o;
    o[0] = (__bf16)a.x; o[1] = (__bf16)a.y; o[2] = (__bf16)a.z; o[3] = (__bf16)a.w;
    o[4] = (__bf16)b.x; o[5] = (__bf16)b.y; o[6] = (__bf16)b.z; o[7] = (__bf16)b.w;
    *(bf16x8*)(xb + idx) = o;
}

// ---------------------------------------------------------------------------
// Transpose-convert Wq|Wv [h][k=512][kk=64] fp32 -> Wt[n=1024][k=512] bf16,
// n = mat*512 + h*64 + kk (fused column index). 64x64 tiles via LDS.
// ---------------------------------------------------------------------------
__global__ __launch_bounds__(256) void conv_wqv(const float* __restrict__ Wq,
                                                const float* __restrict__ Wv,
                                                __bf16* __restrict__ Wt)
{
    __shared__ float T[64][65];
    const int k0  = blockIdx.x * 64;
    const int h   = blockIdx.y;
    const int mat = blockIdx.z;
    const float* src = (mat ? Wv : Wq) + (size_t)h * DMODEL * DHEAD;
    const int tid = threadIdx.x;
#pragma unroll
    for (int it = 0; it < 4; it++) {
        const int kr = it * 16 + (tid >> 4);
        const int c4 = (tid & 15) * 4;
        const float4 v = *(const float4*)(src + (size_t)(k0 + kr) * DHEAD + c4);
        T[kr][c4 + 0] = v.x; T[kr][c4 + 1] = v.y;
        T[kr][c4 + 2] = v.z; T[kr][c4 + 3] = v.w;
    }
    __syncthreads();
    const int c   = tid >> 2;          // kk (src col) -> out row
    const int kk0 = (tid & 3) * 16;
    __bf16* dst = Wt + (size_t)(mat * 512 + h * 64 + c) * DMODEL + k0 + kk0;
    bf16x8 o0, o1;
#pragma unroll
    for (int j = 0; j < 8; j++) o0[j] = (__bf16)T[kk0 + j][c];
#pragma unroll
    for (int j = 0; j < 8; j++) o1[j] = (__bf16)T[kk0 + 8 + j][c];
    *(bf16x8*)dst = o0;
    *(bf16x8*)(dst + 8) = o1;
}

// ---------------------------------------------------------------------------
// Transpose-convert Wup [k=512][n=512] fp32 -> Wt2[n][k] bf16.
// ---------------------------------------------------------------------------
__global__ __launch_bounds__(256) void conv_wup(const float* __restrict__ Wup,
                                                __bf16* __restrict__ Wt)
{
    __shared__ float T[64][65];
    const int k0 = blockIdx.x * 64;   // src rows
    const int n0 = blockIdx.y * 64;   // src cols
    const int tid = threadIdx.x;
#pragma unroll
    for (int it = 0; it < 4; it++) {
        const int kr = it * 16 + (tid >> 4);
        const int c4 = (tid & 15) * 4;
        const float4 v = *(const float4*)(Wup + (size_t)(k0 + kr) * DMODEL + n0 + c4);
        T[kr][c4 + 0] = v.x; T[kr][c4 + 1] = v.y;
        T[kr][c4 + 2] = v.z; T[kr][c4 + 3] = v.w;
    }
    __syncthreads();
    const int c   = tid >> 2;
    const int kk0 = (tid & 3) * 16;
    __bf16* dst = Wt + (size_t)(n0 + c) * DMODEL + k0 + kk0;
    bf16x8 o0, o1;
#pragma unroll
    for (int j = 0; j < 8; j++) o0[j] = (__bf16)T[kk0 + j][c];
#pragma unroll
    for (int j = 0; j < 8; j++) o1[j] = (__bf16)T[kk0 + 8 + j][c];
    *(bf16x8*)dst = o0;
    *(bf16x8*)(dst + 8) = o1;
}

// ---------------------------------------------------------------------------
// Stage 1: MFMA GEMM  Xb[8192x512]bf16 @ Wt^T -> Qt, Vt fp32 dim-major
// [bh*64+kk][4096]. 128x128 tile, BK=32, 4 waves (2x2), 16x16x32 bf16 MFMA,
// global_load_lds width-16 staging into k-contiguous LDS (m97 recipe).
// A-frag: A[m=lane&15][k=quad*8+j]; B-frag from B^T rows; C/D: col=lane&15,
// row=quad*4+reg (verified m89/m91/m120 layouts).
// ---------------------------------------------------------------------------
__global__ __launch_bounds__(256) void gemm_qv_mfma(
    const __bf16* __restrict__ Xb,
    const __bf16* __restrict__ Wt,
    float* __restrict__ Qt,
    float* __restrict__ Vt)
{
    __shared__ __align__(16) __bf16 As[128 * 32];
    __shared__ __align__(16) __bf16 Bs[128 * 32];

    const int tid  = threadIdx.x;
    const int w    = tid >> 6;
    const int lane = tid & 63;
    const int lm   = lane & 15;
    const int q    = lane >> 4;
    const int wm   = w >> 1, wn = w & 1;
    const int row0 = blockIdx.y * 128;
    const int col0 = blockIdx.x * 128;

    const int sr = lane >> 2;          // row within 16-row staging chunk
    const int sc = (lane & 3) * 8;     // k element offset (16 B)
    const __bf16* gA0 = Xb + (size_t)(row0 + w * 32 +  0 + sr) * DMODEL + sc;
    const __bf16* gA1 = Xb + (size_t)(row0 + w * 32 + 16 + sr) * DMODEL + sc;
    const __bf16* gB0 = Wt + (size_t)(col0 + w * 32 +  0 + sr) * DMODEL + sc;
    const __bf16* gB1 = Wt + (size_t)(col0 + w * 32 + 16 + sr) * DMODEL + sc;
    __bf16* lA0 = As + (w * 32 +  0) * 32;
    __bf16* lA1 = As + (w * 32 + 16) * 32;
    __bf16* lB0 = Bs + (w * 32 +  0) * 32;
    __bf16* lB1 = Bs + (w * 32 + 16) * 32;

    f32x4 acc[4][4];
#pragma unroll
    for (int i = 0; i < 4; i++)
#pragma unroll
        for (int j = 0; j < 4; j++) acc[i][j] = (f32x4){0.f, 0.f, 0.f, 0.f};

    for (int k0 = 0; k0 < DMODEL; k0 += 32) {
        __syncthreads();                       // LDS free (prev frags consumed)
        GLOAD_LDS16(gA0, lA0); GLOAD_LDS16(gA1, lA1);
        GLOAD_LDS16(gB0, lB0); GLOAD_LDS16(gB1, lB1);
        gA0 += 32; gA1 += 32; gB0 += 32; gB1 += 32;
        __syncthreads();                       // compiler drains vmcnt here

        bf16x8 af[4], bfr[4];
#pragma unroll
        for (int mi = 0; mi < 4; mi++)
            af[mi] = *(const bf16x8*)&As[(wm * 64 + mi * 16 + lm) * 32 + q * 8];
#pragma unroll
        for (int ni = 0; ni < 4; ni++)
            bfr[ni] = *(const bf16x8*)&Bs[(wn * 64 + ni * 16 + lm) * 32 + q * 8];
#pragma unroll
        for (int mi = 0; mi < 4; mi++)
#pragma unroll
            for (int ni = 0; ni < 4; ni++)
                acc[mi][ni] = __builtin_amdgcn_mfma_f32_16x16x32_bf16(
                    af[mi], bfr[ni], acc[mi][ni], 0, 0, 0);
    }

    // Epilogue: dim index = bb*512 + cc; 4 regs = 4 consecutive tokens -> float4
#pragma unroll
    for (int ni = 0; ni < 4; ni++) {
        const int c  = col0 + wn * 64 + ni * 16 + lm;
        const int cc = c & 511;
        float* outB = (c < 512 ? Qt : Vt);
#pragma unroll
        for (int mi = 0; mi < 4; mi++) {
            const int m  = row0 + wm * 64 + mi * 16 + q * 4;
            const int bb = m >> 12;
            const int nt = m & (N_TOK - 1);
            *(f32x4*)(outB + ((size_t)(bb * 512 + cc)) * N_TOK + nt) = acc[mi][ni];
        }
    }
}

// ---------------------------------------------------------------------------
// Stage 2: banded attention (unchanged compute, per round-3 win) but emits
// heads directly as bf16 row-major [B*N][512] to feed GEMM2's A operand.
// ---------------------------------------------------------------------------
__global__ __launch_bounds__(256) void attn_band(
    const float* __restrict__ Qt,
    const float* __restrict__ Vt,
    __bf16* __restrict__ Hb16)
{
    const int tid  = threadIdx.x;
    const int bh   = blockIdx.x >> 6;          // 0..15
    const int tile = blockIdx.x & 63;          // 64 tokens per block
    const int wv   = tid >> 6;
    const int lane = tid & 63;
    const int p    = lane >> 4;                // dim quarter
    const int il   = lane & 15;
    const int i    = tile * 64 + wv * 16 + il;
    const int b    = bh >> 3;
    const int h    = bh & 7;

    const float* qbase = Qt + ((size_t)bh * DHEAD + p * 16) * N_TOK;
    const float* vbase = Vt + ((size_t)bh * DHEAD + p * 16) * N_TOK;

    float qv[16];
#pragma unroll
    for (int k = 0; k < 16; k++) qv[k] = qbase[(size_t)k * N_TOK + i];

    float c[16];
#pragma unroll
    for (int k = 0; k < 16; k++) c[k] = 0.f;

    float Z = 0.f;
    float vbuf[2][16];

    {
        const int j0 = min(max(i - CTX, 0), N_TOK - 1);
#pragma unroll
        for (int k = 0; k < 16; k++) vbuf[0][k] = vbase[(size_t)k * N_TOK + j0];
    }

#pragma unroll
    for (int d = 0; d < 2 * CTX + 1; d++) {
        if (d < 2 * CTX) {
            const int jn = min(max(i + d + 1 - CTX, 0), N_TOK - 1);
#pragma unroll
            for (int k = 0; k < 16; k++) vbuf[(d + 1) & 1][k] = vbase[(size_t)k * N_TOK + jn];
        }
        const float* v = vbuf[d & 1];
        float s = 0.f;
#pragma unroll
        for (int k = 0; k < 16; k++) s += qv[k] * v[k];
        s += __shfl_xor(s, 16, 64);
        s += __shfl_xor(s, 32, 64);

        const int j = i + d - CTX;
        const bool valid = (d != CTX) && (j >= 0) && (j < N_TOK);
        const float wgt = valid ? __expf(s * 0.0625f) : 0.f;
        Z += wgt;
#pragma unroll
        for (int k = 0; k < 16; k++) c[k] += wgt * v[k];
    }

    const float inv = 1.f / Z;
    __bf16* dst = Hb16 + ((size_t)(b * N_TOK + i)) * DMODEL + h * DHEAD + p * 16;
    bf16x8 o0, o1;
#pragma unroll
    for (int k = 0; k < 8; k++) o0[k] = (__bf16)(c[k] * inv);
#pragma unroll
    for (int k = 0; k < 8; k++) o1[k] = (__bf16)(c[8 + k] * inv);
    *(bf16x8*)dst = o0;
    *(bf16x8*)(dst + 8) = o1;
}

// ---------------------------------------------------------------------------
// Stage 3: MFMA GEMM  Hb16[8192x512] @ Wup -> out fp32 [8192x512].
// 128x64 tile (512 blocks -> 2/CU), 4 waves each owning a 32-row strip.
// ---------------------------------------------------------------------------
__global__ __launch_bounds__(256) void gemm_out_mfma(
    const __bf16* __restrict__ Hb,
    const __bf16* __restrict__ Wt,
    float* __restrict__ out)
{
    __shared__ __align__(16) __bf16 As[128 * 32];
    __shared__ __align__(16) __bf16 Bs[64 * 32];

    const int tid  = threadIdx.x;
    const int w    = tid >> 6;
    const int lane = tid & 63;
    const int lm   = lane & 15;
    const int q    = lane >> 4;
    const int row0 = blockIdx.y * 128;
    const int col0 = blockIdx.x * 64;

    const int sr = lane >> 2;
    const int sc = (lane & 3) * 8;
    const __bf16* gA0 = Hb + (size_t)(row0 + w * 32 +  0 + sr) * DMODEL + sc;
    const __bf16* gA1 = Hb + (size_t)(row0 + w * 32 + 16 + sr) * DMODEL + sc;
    const __bf16* gB0 = Wt + (size_t)(col0 + w * 16 + sr) * DMODEL + sc;
    __bf16* lA0 = As + (w * 32 +  0) * 32;
    __bf16* lA1 = As + (w * 32 + 16) * 32;
    __bf16* lB0 = Bs + (w * 16) * 32;

    f32x4 acc[2][4];
#pragma unroll
    for (int i = 0; i < 2; i++)
#pragma unroll
        for (int j = 0; j < 4; j++) acc[i][j] = (f32x4){0.f, 0.f, 0.f, 0.f};

    for (int k0 = 0; k0 < DMODEL; k0 += 32) {
        __syncthreads();
        GLOAD_LDS16(gA0, lA0); GLOAD_LDS16(gA1, lA1); GLOAD_LDS16(gB0, lB0);
        gA0 += 32; gA1 += 32; gB0 += 32;
        __syncthreads();

        bf16x8 af[2], bfr[4];
#pragma unroll
        for (int mi = 0; mi < 2; mi++)
            af[mi] = *(const bf16x8*)&As[(w * 32 + mi * 16 + lm) * 32 + q * 8];
#pragma unroll
        for (int ni = 0; ni < 4; ni++)
            bfr[ni] = *(const bf16x8*)&Bs[(ni * 16 + lm) * 32 + q * 8];
#pragma unroll
        for (int mi = 0; mi < 2; mi++)
#pragma unroll
            for (int ni = 0; ni < 4; ni++)
                acc[mi][ni] = __builtin_amdgcn_mfma_f32_16x16x32_bf16(
                    af[mi], bfr[ni], acc[mi][ni], 0, 0, 0);
    }

#pragma unroll
    for (int mi = 0; mi < 2; mi++) {
        const int m0 = row0 + w * 32 + mi * 16 + q * 4;
#pragma unroll
        for (int ni = 0; ni < 4; ni++) {
            const int n = col0 + ni * 16 + lm;
#pragma unroll
            for (int r = 0; r < 4; r++)
                out[(size_t)(m0 + r) * DMODEL + n] = acc[mi][ni][r];
        }
    }
}

// ---------------------------------------------------------------------------
extern "C" void kernel_launch(void* const* d_in, const int* in_sizes, int n_in,
                              void* d_out, int out_size, void* d_ws, size_t ws_size,
                              hipStream_t stream)
{
    const float* x   = (const float*)d_in[0];   // [2, 4096, 512]
    const float* Wq  = (const float*)d_in[1];   // [8, 512, 64]
    const float* Wv  = (const float*)d_in[2];   // [8, 512, 64]
    const float* Wup = (const float*)d_in[3];   // [512, 512]
    float* out = (float*)d_out;                 // [2, 4096, 512]

    const size_t QV = (size_t)2 * NHEAD * N_TOK * DHEAD;   // 4,194,304
    float*  Qt   = (float*)d_ws;                           // 16.78 MB
    float*  Vt   = Qt + QV;                                // 16.78 MB
    __bf16* Xb   = (__bf16*)(Vt + QV);                     // 8 MB
    __bf16* Hb16 = Xb;                                     // alias: Xb dead after gemm_qv
    __bf16* Wtqv = Xb + (size_t)NROW * DMODEL;             // 1 MB
    __bf16* Wtup = Wtqv + (size_t)1024 * DMODEL;           // 0.5 MB

    dim3 blk(256);
    conv_x   <<<dim3(2048),    blk, 0, stream>>>(x, Xb);
    conv_wqv <<<dim3(8, 8, 2), blk, 0, stream>>>(Wq, Wv, Wtqv);
    conv_wup <<<dim3(8, 8),    blk, 0, stream>>>(Wup, Wtup);
    gemm_qv_mfma <<<dim3(8, 64), blk, 0, stream>>>(Xb, Wtqv, Qt, Vt);
    attn_band    <<<dim3(1024),  blk, 0, stream>>>(Qt, Vt, Hb16);
    gemm_out_mfma<<<dim3(8, 64), blk, 0, stream>>>(Hb16, Wtup, out);
}

// Round 5
// 128.278 us; speedup vs baseline: 3.3271x; 1.2330x over previous
//
#include <hip/hip_runtime.h>
#include <math.h>

#define N_TOK 4096
#define DMODEL 512
#define NHEAD 8
#define DHEAD 64
#define CTX 10
#define NROW 8192  // B * N_TOK

typedef __bf16 bf16x8 __attribute__((ext_vector_type(8)));
typedef float  f32x4  __attribute__((ext_vector_type(4)));

#define GLOAD_LDS16(g, l) __builtin_amdgcn_global_load_lds(                 \
    (const __attribute__((address_space(1))) void*)(g),                     \
    (__attribute__((address_space(3))) void*)(l), 16, 0, 0)

// ---------------------------------------------------------------------------
// Convert x (fp32 row-major [8192][512]) -> bf16 same layout.
// ---------------------------------------------------------------------------
__global__ __launch_bounds__(256) void conv_x(const float* __restrict__ x,
                                              __bf16* __restrict__ xb)
{
    const int idx = (blockIdx.x * 256 + threadIdx.x) * 8;
    const float4 a = *(const float4*)(x + idx);
    const float4 b = *(const float4*)(x + idx + 4);
    bf16x8 o;
    o[0] = (__bf16)a.x; o[1] = (__bf16)a.y; o[2] = (__bf16)a.z; o[3] = (__bf16)a.w;
    o[4] = (__bf16)b.x; o[5] = (__bf16)b.y; o[6] = (__bf16)b.z; o[7] = (__bf16)b.w;
    *(bf16x8*)(xb + idx) = o;
}

// ---------------------------------------------------------------------------
// Transpose-convert Wq|Wv [h][k=512][kk=64] fp32 -> Wt[n=1024][k=512] bf16.
// ---------------------------------------------------------------------------
__global__ __launch_bounds__(256) void conv_wqv(const float* __restrict__ Wq,
                                                const float* __restrict__ Wv,
                                                __bf16* __restrict__ Wt)
{
    __shared__ float T[64][65];
    const int k0  = blockIdx.x * 64;
    const int h   = blockIdx.y;
    const int mat = blockIdx.z;
    const float* src = (mat ? Wv : Wq) + (size_t)h * DMODEL * DHEAD;
    const int tid = threadIdx.x;
#pragma unroll
    for (int it = 0; it < 4; it++) {
        const int kr = it * 16 + (tid >> 4);
        const int c4 = (tid & 15) * 4;
        const float4 v = *(const float4*)(src + (size_t)(k0 + kr) * DHEAD + c4);
        T[kr][c4 + 0] = v.x; T[kr][c4 + 1] = v.y;
        T[kr][c4 + 2] = v.z; T[kr][c4 + 3] = v.w;
    }
    __syncthreads();
    const int c   = tid >> 2;
    const int kk0 = (tid & 3) * 16;
    __bf16* dst = Wt + (size_t)(mat * 512 + h * 64 + c) * DMODEL + k0 + kk0;
    bf16x8 o0, o1;
#pragma unroll
    for (int j = 0; j < 8; j++) o0[j] = (__bf16)T[kk0 + j][c];
#pragma unroll
    for (int j = 0; j < 8; j++) o1[j] = (__bf16)T[kk0 + 8 + j][c];
    *(bf16x8*)dst = o0;
    *(bf16x8*)(dst + 8) = o1;
}

// ---------------------------------------------------------------------------
// Transpose-convert Wup [k=512][n=512] fp32 -> Wt2[n][k] bf16.
// ---------------------------------------------------------------------------
__global__ __launch_bounds__(256) void conv_wup(const float* __restrict__ Wup,
                                                __bf16* __restrict__ Wt)
{
    __shared__ float T[64][65];
    const int k0 = blockIdx.x * 64;
    const int n0 = blockIdx.y * 64;
    const int tid = threadIdx.x;
#pragma unroll
    for (int it = 0; it < 4; it++) {
        const int kr = it * 16 + (tid >> 4);
        const int c4 = (tid & 15) * 4;
        const float4 v = *(const float4*)(Wup + (size_t)(k0 + kr) * DMODEL + n0 + c4);
        T[kr][c4 + 0] = v.x; T[kr][c4 + 1] = v.y;
        T[kr][c4 + 2] = v.z; T[kr][c4 + 3] = v.w;
    }
    __syncthreads();
    const int c   = tid >> 2;
    const int kk0 = (tid & 3) * 16;
    __bf16* dst = Wt + (size_t)(n0 + c) * DMODEL + k0 + kk0;
    bf16x8 o0, o1;
#pragma unroll
    for (int j = 0; j < 8; j++) o0[j] = (__bf16)T[kk0 + j][c];
#pragma unroll
    for (int j = 0; j < 8; j++) o1[j] = (__bf16)T[kk0 + 8 + j][c];
    *(bf16x8*)dst = o0;
    *(bf16x8*)(dst + 8) = o1;
}

// ---------------------------------------------------------------------------
// Stage 1: MFMA GEMM  Xb[8192x512]bf16 @ Wt^T -> Qt, Vt fp32 dim-major.
// ---------------------------------------------------------------------------
__global__ __launch_bounds__(256) void gemm_qv_mfma(
    const __bf16* __restrict__ Xb,
    const __bf16* __restrict__ Wt,
    float* __restrict__ Qt,
    float* __restrict__ Vt)
{
    __shared__ __align__(16) __bf16 As[128 * 32];
    __shared__ __align__(16) __bf16 Bs[128 * 32];

    const int tid  = threadIdx.x;
    const int w    = tid >> 6;
    const int lane = tid & 63;
    const int lm   = lane & 15;
    const int q    = lane >> 4;
    const int wm   = w >> 1, wn = w & 1;
    const int row0 = blockIdx.y * 128;
    const int col0 = blockIdx.x * 128;

    const int sr = lane >> 2;
    const int sc = (lane & 3) * 8;
    const __bf16* gA0 = Xb + (size_t)(row0 + w * 32 +  0 + sr) * DMODEL + sc;
    const __bf16* gA1 = Xb + (size_t)(row0 + w * 32 + 16 + sr) * DMODEL + sc;
    const __bf16* gB0 = Wt + (size_t)(col0 + w * 32 +  0 + sr) * DMODEL + sc;
    const __bf16* gB1 = Wt + (size_t)(col0 + w * 32 + 16 + sr) * DMODEL + sc;
    __bf16* lA0 = As + (w * 32 +  0) * 32;
    __bf16* lA1 = As + (w * 32 + 16) * 32;
    __bf16* lB0 = Bs + (w * 32 +  0) * 32;
    __bf16* lB1 = Bs + (w * 32 + 16) * 32;

    f32x4 acc[4][4];
#pragma unroll
    for (int i = 0; i < 4; i++)
#pragma unroll
        for (int j = 0; j < 4; j++) acc[i][j] = (f32x4){0.f, 0.f, 0.f, 0.f};

    for (int k0 = 0; k0 < DMODEL; k0 += 32) {
        __syncthreads();
        GLOAD_LDS16(gA0, lA0); GLOAD_LDS16(gA1, lA1);
        GLOAD_LDS16(gB0, lB0); GLOAD_LDS16(gB1, lB1);
        gA0 += 32; gA1 += 32; gB0 += 32; gB1 += 32;
        __syncthreads();

        bf16x8 af[4], bfr[4];
#pragma unroll
        for (int mi = 0; mi < 4; mi++)
            af[mi] = *(const bf16x8*)&As[(wm * 64 + mi * 16 + lm) * 32 + q * 8];
#pragma unroll
        for (int ni = 0; ni < 4; ni++)
            bfr[ni] = *(const bf16x8*)&Bs[(wn * 64 + ni * 16 + lm) * 32 + q * 8];
#pragma unroll
        for (int mi = 0; mi < 4; mi++)
#pragma unroll
            for (int ni = 0; ni < 4; ni++)
                acc[mi][ni] = __builtin_amdgcn_mfma_f32_16x16x32_bf16(
                    af[mi], bfr[ni], acc[mi][ni], 0, 0, 0);
    }

#pragma unroll
    for (int ni = 0; ni < 4; ni++) {
        const int c  = col0 + wn * 64 + ni * 16 + lm;
        const int cc = c & 511;
        float* outB = (c < 512 ? Qt : Vt);
#pragma unroll
        for (int mi = 0; mi < 4; mi++) {
            const int m  = row0 + wm * 64 + mi * 16 + q * 4;
            const int bb = m >> 12;
            const int nt = m & (N_TOK - 1);
            *(f32x4*)(outB + ((size_t)(bb * 512 + cc)) * N_TOK + nt) = acc[mi][ni];
        }
    }
}

// ---------------------------------------------------------------------------
// Stage 2: banded attention, LDS-staged V band.
// Block = 64 tokens x 1 head, 256 threads (4 threads/token, 16 dims each).
// V[64 dims][96 slots] staged in LDS (halo +-12, clamped; invalid taps get
// weight 0 so clamped garbage never contributes). Row stride 97 (odd) ->
// the quarter-split ds_read pattern is 2-way bank aliasing = free (m136).
// Round-4 failure mode fixed: 21-tap loop reads LDS (no global latency),
// partial unroll keeps VGPR ~100 (was 216 -> 10% occupancy).
// ---------------------------------------------------------------------------
#define VSTRIDE 97
__global__ __launch_bounds__(256) void attn_band(
    const float* __restrict__ Qt,
    const float* __restrict__ Vt,
    __bf16* __restrict__ Hb16)
{
    __shared__ float Vs[64 * VSTRIDE];   // 24,832 B

    const int tid  = threadIdx.x;
    const int bh   = blockIdx.x >> 6;          // 0..15
    const int tile = blockIdx.x & 63;          // 0..63, 64 tokens each
    const int i0   = tile * 64;
    const int b    = bh >> 3;
    const int h    = bh & 7;

    // ---- stage V band: dims 0..63, token slots tok0 .. tok0+95 (clamped)
    const float* vband = Vt + (size_t)bh * DHEAD * N_TOK;
    const int tok0 = i0 - 12;
#pragma unroll
    for (int it = 0; it < 6; it++) {
        const int idx = it * 256 + tid;        // 0..1535
        const int k   = idx / 24;              // dim
        const int s4  = idx - k * 24;          // float4 slot
        const int tokg = tok0 + s4 * 4;
        const int tokc = min(max(tokg, 0), N_TOK - 4);
        const float4 v = *(const float4*)(vband + (size_t)k * N_TOK + tokc);
        float* dst = &Vs[k * VSTRIDE + s4 * 4];
        dst[0] = v.x; dst[1] = v.y; dst[2] = v.z; dst[3] = v.w;
    }

    const int lane = tid & 63;
    const int wv   = tid >> 6;                 // 0..3
    const int il   = lane & 15;
    const int p    = lane >> 4;                // dim quarter
    const int i    = i0 + wv * 16 + il;        // token
    const int slot0 = wv * 16 + il + 2;        // LDS slot of tap d=0

    // ---- Q fragment (global, coalesced, one-time)
    const float* qbase = Qt + ((size_t)bh * DHEAD + p * 16) * N_TOK;
    float qv[16];
#pragma unroll
    for (int k = 0; k < 16; k++) qv[k] = qbase[(size_t)k * N_TOK + i];

    __syncthreads();

    float c[16];
#pragma unroll
    for (int k = 0; k < 16; k++) c[k] = 0.f;
    float Z = 0.f;

#pragma unroll 3
    for (int d = 0; d < 2 * CTX + 1; d++) {
        const float* vrow = &Vs[p * 16 * VSTRIDE + slot0 + d];
        float v[16];
#pragma unroll
        for (int k = 0; k < 16; k++) v[k] = vrow[k * VSTRIDE];
        float s = 0.f;
#pragma unroll
        for (int k = 0; k < 16; k++) s += qv[k] * v[k];
        s += __shfl_xor(s, 16, 64);
        s += __shfl_xor(s, 32, 64);

        const int j = i + d - CTX;
        const bool valid = (d != CTX) && (j >= 0) && (j < N_TOK);
        const float w = valid ? __expf(s * 0.0625f) : 0.f;
        Z += w;
#pragma unroll
        for (int k = 0; k < 16; k++) c[k] += w * v[k];
    }

    const float inv = 1.f / Z;
    __bf16* dst = Hb16 + ((size_t)(b * N_TOK + i)) * DMODEL + h * DHEAD + p * 16;
    bf16x8 o0, o1;
#pragma unroll
    for (int k = 0; k < 8; k++) o0[k] = (__bf16)(c[k] * inv);
#pragma unroll
    for (int k = 0; k < 8; k++) o1[k] = (__bf16)(c[8 + k] * inv);
    *(bf16x8*)dst = o0;
    *(bf16x8*)(dst + 8) = o1;
}

// ---------------------------------------------------------------------------
// Stage 3: MFMA GEMM  Hb16[8192x512] @ Wup -> out fp32 [8192x512].
// ---------------------------------------------------------------------------
__global__ __launch_bounds__(256) void gemm_out_mfma(
    const __bf16* __restrict__ Hb,
    const __bf16* __restrict__ Wt,
    float* __restrict__ out)
{
    __shared__ __align__(16) __bf16 As[128 * 32];
    __shared__ __align__(16) __bf16 Bs[64 * 32];

    const int tid  = threadIdx.x;
    const int w    = tid >> 6;
    const int lane = tid & 63;
    const int lm   = lane & 15;
    const int q    = lane >> 4;
    const int row0 = blockIdx.y * 128;
    const int col0 = blockIdx.x * 64;

    const int sr = lane >> 2;
    const int sc = (lane & 3) * 8;
    const __bf16* gA0 = Hb + (size_t)(row0 + w * 32 +  0 + sr) * DMODEL + sc;
    const __bf16* gA1 = Hb + (size_t)(row0 + w * 32 + 16 + sr) * DMODEL + sc;
    const __bf16* gB0 = Wt + (size_t)(col0 + w * 16 + sr) * DMODEL + sc;
    __bf16* lA0 = As + (w * 32 +  0) * 32;
    __bf16* lA1 = As + (w * 32 + 16) * 32;
    __bf16* lB0 = Bs + (w * 16) * 32;

    f32x4 acc[2][4];
#pragma unroll
    for (int i = 0; i < 2; i++)
#pragma unroll
        for (int j = 0; j < 4; j++) acc[i][j] = (f32x4){0.f, 0.f, 0.f, 0.f};

    for (int k0 = 0; k0 < DMODEL; k0 += 32) {
        __syncthreads();
        GLOAD_LDS16(gA0, lA0); GLOAD_LDS16(gA1, lA1); GLOAD_LDS16(gB0, lB0);
        gA0 += 32; gA1 += 32; gB0 += 32;
        __syncthreads();

        bf16x8 af[2], bfr[4];
#pragma unroll
        for (int mi = 0; mi < 2; mi++)
            af[mi] = *(const bf16x8*)&As[(w * 32 + mi * 16 + lm) * 32 + q * 8];
#pragma unroll
        for (int ni = 0; ni < 4; ni++)
            bfr[ni] = *(const bf16x8*)&Bs[(ni * 16 + lm) * 32 + q * 8];
#pragma unroll
        for (int mi = 0; mi < 2; mi++)
#pragma unroll
            for (int ni = 0; ni < 4; ni++)
                acc[mi][ni] = __builtin_amdgcn_mfma_f32_16x16x32_bf16(
                    af[mi], bfr[ni], acc[mi][ni], 0, 0, 0);
    }

#pragma unroll
    for (int mi = 0; mi < 2; mi++) {
        const int m0 = row0 + w * 32 + mi * 16 + q * 4;
#pragma unroll
        for (int ni = 0; ni < 4; ni++) {
            const int n = col0 + ni * 16 + lm;
#pragma unroll
            for (int r = 0; r < 4; r++)
                out[(size_t)(m0 + r) * DMODEL + n] = acc[mi][ni][r];
        }
    }
}

// ---------------------------------------------------------------------------
extern "C" void kernel_launch(void* const* d_in, const int* in_sizes, int n_in,
                              void* d_out, int out_size, void* d_ws, size_t ws_size,
                              hipStream_t stream)
{
    const float* x   = (const float*)d_in[0];
    const float* Wq  = (const float*)d_in[1];
    const float* Wv  = (const float*)d_in[2];
    const float* Wup = (const float*)d_in[3];
    float* out = (float*)d_out;

    const size_t QV = (size_t)2 * NHEAD * N_TOK * DHEAD;
    float*  Qt   = (float*)d_ws;
    float*  Vt   = Qt + QV;
    __bf16* Xb   = (__bf16*)(Vt + QV);
    __bf16* Hb16 = Xb;                         // alias: Xb dead after gemm_qv
    __bf16* Wtqv = Xb + (size_t)NROW * DMODEL;
    __bf16* Wtup = Wtqv + (size_t)1024 * DMODEL;

    dim3 blk(256);
    conv_x   <<<dim3(2048),    blk, 0, stream>>>(x, Xb);
    conv_wqv <<<dim3(8, 8, 2), blk, 0, stream>>>(Wq, Wv, Wtqv);
    conv_wup <<<dim3(8, 8),    blk, 0, stream>>>(Wup, Wtup);
    gemm_qv_mfma <<<dim3(8, 64), blk, 0, stream>>>(Xb, Wtqv, Qt, Vt);
    attn_band    <<<dim3(1024),  blk, 0, stream>>>(Qt, Vt, Hb16);
    gemm_out_mfma<<<dim3(8, 64), blk, 0, stream>>>(Hb16, Wtup, out);
}

// Round 6
// 126.865 us; speedup vs baseline: 3.3642x; 1.0111x over previous
//
#include <hip/hip_runtime.h>
#include <math.h>

#define N_TOK 4096
#define DMODEL 512
#define NHEAD 8
#define DHEAD 64
#define CTX 10
#define NROW 8192  // B * N_TOK

typedef __bf16 bf16x4 __attribute__((ext_vector_type(4)));
typedef __bf16 bf16x8 __attribute__((ext_vector_type(8)));
typedef float  f32x4  __attribute__((ext_vector_type(4)));

#define GLOAD_LDS16(g, l) __builtin_amdgcn_global_load_lds(                 \
    (const __attribute__((address_space(1))) void*)(g),                     \
    (__attribute__((address_space(3))) void*)(l), 16, 0, 0)

// ---------------------------------------------------------------------------
// Merged weight transpose-convert (one launch instead of two):
//   blocks [0,128):  Wq|Wv [h][k=512][kk=64] fp32 -> Wtqv[n=1024][k=512] bf16
//   blocks [128,192): Wup [k=512][n=512] fp32     -> Wtup[n=512][k=512] bf16
// ---------------------------------------------------------------------------
__global__ __launch_bounds__(256) void conv_w(const float* __restrict__ Wq,
                                              const float* __restrict__ Wv,
                                              const float* __restrict__ Wup,
                                              __bf16* __restrict__ Wtqv,
                                              __bf16* __restrict__ Wtup)
{
    __shared__ float T[64][65];
    const int tid = threadIdx.x;
    const int bid = blockIdx.x;

    const float* src;
    __bf16* dstBase;
    int k0, rowScale;   // dst row = rowBase + c, row stride DMODEL
    int rowBase;
    int srcStride;      // floats per src row
    if (bid < 128) {
        k0 = (bid & 7) * 64;
        const int h   = (bid >> 3) & 7;
        const int mat = bid >> 6;
        src = (mat ? Wv : Wq) + (size_t)h * DMODEL * DHEAD;
        dstBase = Wtqv;
        rowBase = mat * 512 + h * 64;
        srcStride = DHEAD;
        rowScale = 1;
    } else {
        const int b2 = bid - 128;
        k0 = (b2 & 7) * 64;
        const int n0 = (b2 >> 3) * 64;
        src = Wup + n0;
        dstBase = Wtup;
        rowBase = n0;
        srcStride = DMODEL;
        rowScale = 1;
    }
    (void)rowScale;

#pragma unroll
    for (int it = 0; it < 4; it++) {
        const int kr = it * 16 + (tid >> 4);
        const int c4 = (tid & 15) * 4;
        const float4 v = *(const float4*)(src + (size_t)(k0 + kr) * srcStride + c4);
        T[kr][c4 + 0] = v.x; T[kr][c4 + 1] = v.y;
        T[kr][c4 + 2] = v.z; T[kr][c4 + 3] = v.w;
    }
    __syncthreads();
    const int c   = tid >> 2;
    const int kk0 = (tid & 3) * 16;
    __bf16* dst = dstBase + (size_t)(rowBase + c) * DMODEL + k0 + kk0;
    bf16x8 o0, o1;
#pragma unroll
    for (int j = 0; j < 8; j++) o0[j] = (__bf16)T[kk0 + j][c];
#pragma unroll
    for (int j = 0; j < 8; j++) o1[j] = (__bf16)T[kk0 + 8 + j][c];
    *(bf16x8*)dst = o0;
    *(bf16x8*)(dst + 8) = o1;
}

// ---------------------------------------------------------------------------
// Stage 1: MFMA GEMM  x[8192x512]fp32 @ Wt^T -> Qt, Vt fp32 dim-major.
// A is staged straight from fp32 x: coalesced float4 loads (8 lanes/row,
// 16 full lines per instr) -> cvt bf16 -> ds_write_b64 (linear, conflict-
// free). This removed the conv_x pre-pass (34 MB HBM roundtrip + a launch).
// B (pre-converted weights) keeps the global_load_lds DMA path.
// ---------------------------------------------------------------------------
__global__ __launch_bounds__(256) void gemm_qv_mfma(
    const float* __restrict__ x,
    const __bf16* __restrict__ Wt,
    float* __restrict__ Qt,
    float* __restrict__ Vt)
{
    __shared__ __align__(16) __bf16 As[128 * 32];
    __shared__ __align__(16) __bf16 Bs[128 * 32];

    const int tid  = threadIdx.x;
    const int w    = tid >> 6;
    const int lane = tid & 63;
    const int lm   = lane & 15;
    const int q    = lane >> 4;
    const int wm   = w >> 1, wn = w & 1;
    const int row0 = blockIdx.y * 128;
    const int col0 = blockIdx.x * 128;

    // A staging map: 4 passes x (32 rows x 32 k) per K-iter
    const int asr = tid >> 3;          // 0..31 row within pass
    const int asc = (tid & 7) * 4;     // k float offset
    const float* gA = x + (size_t)(row0 + asr) * DMODEL + asc;

    // B staging map (global_load_lds width 16)
    const int sr = lane >> 2;
    const int sc = (lane & 3) * 8;
    const __bf16* gB0 = Wt + (size_t)(col0 + w * 32 +  0 + sr) * DMODEL + sc;
    const __bf16* gB1 = Wt + (size_t)(col0 + w * 32 + 16 + sr) * DMODEL + sc;
    __bf16* lB0 = Bs + (w * 32 +  0) * 32;
    __bf16* lB1 = Bs + (w * 32 + 16) * 32;

    f32x4 acc[4][4];
#pragma unroll
    for (int i = 0; i < 4; i++)
#pragma unroll
        for (int j = 0; j < 4; j++) acc[i][j] = (f32x4){0.f, 0.f, 0.f, 0.f};

    for (int k0 = 0; k0 < DMODEL; k0 += 32) {
        float4 a[4];
#pragma unroll
        for (int p = 0; p < 4; p++)
            a[p] = *(const float4*)(gA + (size_t)p * 32 * DMODEL);
        gA += 32;

        __syncthreads();               // prev iteration's LDS reads complete
#pragma unroll
        for (int p = 0; p < 4; p++) {
            bf16x4 o;
            o[0] = (__bf16)a[p].x; o[1] = (__bf16)a[p].y;
            o[2] = (__bf16)a[p].z; o[3] = (__bf16)a[p].w;
            *(bf16x4*)&As[(asr + p * 32) * 32 + asc] = o;
        }
        GLOAD_LDS16(gB0, lB0); GLOAD_LDS16(gB1, lB1);
        gB0 += 32; gB1 += 32;
        __syncthreads();               // drains vmcnt + lgkmcnt

        bf16x8 af[4], bfr[4];
#pragma unroll
        for (int mi = 0; mi < 4; mi++)
            af[mi] = *(const bf16x8*)&As[(wm * 64 + mi * 16 + lm) * 32 + q * 8];
#pragma unroll
        for (int ni = 0; ni < 4; ni++)
            bfr[ni] = *(const bf16x8*)&Bs[(wn * 64 + ni * 16 + lm) * 32 + q * 8];
#pragma unroll
        for (int mi = 0; mi < 4; mi++)
#pragma unroll
            for (int ni = 0; ni < 4; ni++)
                acc[mi][ni] = __builtin_amdgcn_mfma_f32_16x16x32_bf16(
                    af[mi], bfr[ni], acc[mi][ni], 0, 0, 0);
    }

    // Epilogue: dim-major scatter [bb*512+cc][token], float4 along tokens
#pragma unroll
    for (int ni = 0; ni < 4; ni++) {
        const int c  = col0 + wn * 64 + ni * 16 + lm;
        const int cc = c & 511;
        float* outB = (c < 512 ? Qt : Vt);
#pragma unroll
        for (int mi = 0; mi < 4; mi++) {
            const int m  = row0 + wm * 64 + mi * 16 + q * 4;
            const int bb = m >> 12;
            const int nt = m & (N_TOK - 1);
            *(f32x4*)(outB + ((size_t)(bb * 512 + cc)) * N_TOK + nt) = acc[mi][ni];
        }
    }
}

// ---------------------------------------------------------------------------
// Stage 2: banded attention, LDS-staged V band (round-5 win, unchanged).
// Block = 64 tokens x 1 head; V[64 dims][96 slots] in LDS, stride 97.
// ---------------------------------------------------------------------------
#define VSTRIDE 97
__global__ __launch_bounds__(256) void attn_band(
    const float* __restrict__ Qt,
    const float* __restrict__ Vt,
    __bf16* __restrict__ Hb16)
{
    __shared__ float Vs[64 * VSTRIDE];   // 24,832 B

    const int tid  = threadIdx.x;
    const int bh   = blockIdx.x >> 6;
    const int tile = blockIdx.x & 63;
    const int i0   = tile * 64;
    const int b    = bh >> 3;
    const int h    = bh & 7;

    const float* vband = Vt + (size_t)bh * DHEAD * N_TOK;
    const int tok0 = i0 - 12;
#pragma unroll
    for (int it = 0; it < 6; it++) {
        const int idx = it * 256 + tid;
        const int k   = idx / 24;
        const int s4  = idx - k * 24;
        const int tokg = tok0 + s4 * 4;
        const int tokc = min(max(tokg, 0), N_TOK - 4);
        const float4 v = *(const float4*)(vband + (size_t)k * N_TOK + tokc);
        float* dst = &Vs[k * VSTRIDE + s4 * 4];
        dst[0] = v.x; dst[1] = v.y; dst[2] = v.z; dst[3] = v.w;
    }

    const int lane = tid & 63;
    const int wv   = tid >> 6;
    const int il   = lane & 15;
    const int p    = lane >> 4;
    const int i    = i0 + wv * 16 + il;
    const int slot0 = wv * 16 + il + 2;

    const float* qbase = Qt + ((size_t)bh * DHEAD + p * 16) * N_TOK;
    float qv[16];
#pragma unroll
    for (int k = 0; k < 16; k++) qv[k] = qbase[(size_t)k * N_TOK + i];

    __syncthreads();

    float c[16];
#pragma unroll
    for (int k = 0; k < 16; k++) c[k] = 0.f;
    float Z = 0.f;

#pragma unroll 3
    for (int d = 0; d < 2 * CTX + 1; d++) {
        const float* vrow = &Vs[p * 16 * VSTRIDE + slot0 + d];
        float v[16];
#pragma unroll
        for (int k = 0; k < 16; k++) v[k] = vrow[k * VSTRIDE];
        float s = 0.f;
#pragma unroll
        for (int k = 0; k < 16; k++) s += qv[k] * v[k];
        s += __shfl_xor(s, 16, 64);
        s += __shfl_xor(s, 32, 64);

        const int j = i + d - CTX;
        const bool valid = (d != CTX) && (j >= 0) && (j < N_TOK);
        const float w = valid ? __expf(s * 0.0625f) : 0.f;
        Z += w;
#pragma unroll
        for (int k = 0; k < 16; k++) c[k] += w * v[k];
    }

    const float inv = 1.f / Z;
    __bf16* dst = Hb16 + ((size_t)(b * N_TOK + i)) * DMODEL + h * DHEAD + p * 16;
    bf16x8 o0, o1;
#pragma unroll
    for (int k = 0; k < 8; k++) o0[k] = (__bf16)(c[k] * inv);
#pragma unroll
    for (int k = 0; k < 8; k++) o1[k] = (__bf16)(c[8 + k] * inv);
    *(bf16x8*)dst = o0;
    *(bf16x8*)(dst + 8) = o1;
}

// ---------------------------------------------------------------------------
// Stage 3: MFMA GEMM  Hb16[8192x512] @ Wup -> out fp32 [8192x512].
// ---------------------------------------------------------------------------
__global__ __launch_bounds__(256) void gemm_out_mfma(
    const __bf16* __restrict__ Hb,
    const __bf16* __restrict__ Wt,
    float* __restrict__ out)
{
    __shared__ __align__(16) __bf16 As[128 * 32];
    __shared__ __align__(16) __bf16 Bs[64 * 32];

    const int tid  = threadIdx.x;
    const int w    = tid >> 6;
    const int lane = tid & 63;
    const int lm   = lane & 15;
    const int q    = lane >> 4;
    const int row0 = blockIdx.y * 128;
    const int col0 = blockIdx.x * 64;

    const int sr = lane >> 2;
    const int sc = (lane & 3) * 8;
    const __bf16* gA0 = Hb + (size_t)(row0 + w * 32 +  0 + sr) * DMODEL + sc;
    const __bf16* gA1 = Hb + (size_t)(row0 + w * 32 + 16 + sr) * DMODEL + sc;
    const __bf16* gB0 = Wt + (size_t)(col0 + w * 16 + sr) * DMODEL + sc;
    __bf16* lA0 = As + (w * 32 +  0) * 32;
    __bf16* lA1 = As + (w * 32 + 16) * 32;
    __bf16* lB0 = Bs + (w * 16) * 32;

    f32x4 acc[2][4];
#pragma unroll
    for (int i = 0; i < 2; i++)
#pragma unroll
        for (int j = 0; j < 4; j++) acc[i][j] = (f32x4){0.f, 0.f, 0.f, 0.f};

    for (int k0 = 0; k0 < DMODEL; k0 += 32) {
        __syncthreads();
        GLOAD_LDS16(gA0, lA0); GLOAD_LDS16(gA1, lA1); GLOAD_LDS16(gB0, lB0);
        gA0 += 32; gA1 += 32; gB0 += 32;
        __syncthreads();

        bf16x8 af[2], bfr[4];
#pragma unroll
        for (int mi = 0; mi < 2; mi++)
            af[mi] = *(const bf16x8*)&As[(w * 32 + mi * 16 + lm) * 32 + q * 8];
#pragma unroll
        for (int ni = 0; ni < 4; ni++)
            bfr[ni] = *(const bf16x8*)&Bs[(ni * 16 + lm) * 32 + q * 8];
#pragma unroll
        for (int mi = 0; mi < 2; mi++)
#pragma unroll
            for (int ni = 0; ni < 4; ni++)
                acc[mi][ni] = __builtin_amdgcn_mfma_f32_16x16x32_bf16(
                    af[mi], bfr[ni], acc[mi][ni], 0, 0, 0);
    }

#pragma unroll
    for (int mi = 0; mi < 2; mi++) {
        const int m0 = row0 + w * 32 + mi * 16 + q * 4;
#pragma unroll
        for (int ni = 0; ni < 4; ni++) {
            const int n = col0 + ni * 16 + lm;
#pragma unroll
            for (int r = 0; r < 4; r++)
                out[(size_t)(m0 + r) * DMODEL + n] = acc[mi][ni][r];
        }
    }
}

// ---------------------------------------------------------------------------
extern "C" void kernel_launch(void* const* d_in, const int* in_sizes, int n_in,
                              void* d_out, int out_size, void* d_ws, size_t ws_size,
                              hipStream_t stream)
{
    const float* x   = (const float*)d_in[0];
    const float* Wq  = (const float*)d_in[1];
    const float* Wv  = (const float*)d_in[2];
    const float* Wup = (const float*)d_in[3];
    float* out = (float*)d_out;

    const size_t QV = (size_t)2 * NHEAD * N_TOK * DHEAD;
    float*  Qt   = (float*)d_ws;                           // 16.78 MB
    float*  Vt   = Qt + QV;                                // 16.78 MB
    __bf16* Hb16 = (__bf16*)(Vt + QV);                     // 8.39 MB
    __bf16* Wtqv = Hb16 + (size_t)NROW * DMODEL;           // 1.05 MB
    __bf16* Wtup = Wtqv + (size_t)1024 * DMODEL;           // 0.52 MB

    dim3 blk(256);
    conv_w       <<<dim3(192),   blk, 0, stream>>>(Wq, Wv, Wup, Wtqv, Wtup);
    gemm_qv_mfma <<<dim3(8, 64), blk, 0, stream>>>(x, Wtqv, Qt, Vt);
    attn_band    <<<dim3(1024),  blk, 0, stream>>>(Qt, Vt, Hb16);
    gemm_out_mfma<<<dim3(8, 64), blk, 0, stream>>>(Hb16, Wtup, out);
}

// Round 8
// 124.862 us; speedup vs baseline: 3.4181x; 1.0160x over previous
//
#include <hip/hip_runtime.h>
#include <math.h>

#define N_TOK 4096
#define DMODEL 512
#define NHEAD 8
#define DHEAD 64
#define CTX 10
#define NROW 8192  // B * N_TOK

typedef __bf16 bf16x4 __attribute__((ext_vector_type(4)));
typedef __bf16 bf16x8 __attribute__((ext_vector_type(8)));
typedef float  f32x4  __attribute__((ext_vector_type(4)));

#define GLOAD_LDS16(g, l) __builtin_amdgcn_global_load_lds(                 \
    (const __attribute__((address_space(1))) void*)(g),                     \
    (__attribute__((address_space(3))) void*)(l), 16, 0, 0)

// ---------------------------------------------------------------------------
// Merged weight transpose-convert:
//   blocks [0,128):  Wq|Wv [h][k=512][kk=64] fp32 -> Wtqv[n=1024][k=512] bf16
//   blocks [128,192): Wup [k=512][n=512] fp32     -> Wtup[n=512][k=512] bf16
// ---------------------------------------------------------------------------
__global__ __launch_bounds__(256) void conv_w(const float* __restrict__ Wq,
                                              const float* __restrict__ Wv,
                                              const float* __restrict__ Wup,
                                              __bf16* __restrict__ Wtqv,
                                              __bf16* __restrict__ Wtup)
{
    __shared__ float T[64][65];
    const int tid = threadIdx.x;
    const int bid = blockIdx.x;

    const float* src;
    __bf16* dstBase;
    int k0, rowBase, srcStride;
    if (bid < 128) {
        k0 = (bid & 7) * 64;
        const int h   = (bid >> 3) & 7;
        const int mat = bid >> 6;
        src = (mat ? Wv : Wq) + (size_t)h * DMODEL * DHEAD;
        dstBase = Wtqv;
        rowBase = mat * 512 + h * 64;
        srcStride = DHEAD;
    } else {
        const int b2 = bid - 128;
        k0 = (b2 & 7) * 64;
        const int n0 = (b2 >> 3) * 64;
        src = Wup + n0;
        dstBase = Wtup;
        rowBase = n0;
        srcStride = DMODEL;
    }

#pragma unroll
    for (int it = 0; it < 4; it++) {
        const int kr = it * 16 + (tid >> 4);
        const int c4 = (tid & 15) * 4;
        const float4 v = *(const float4*)(src + (size_t)(k0 + kr) * srcStride + c4);
        T[kr][c4 + 0] = v.x; T[kr][c4 + 1] = v.y;
        T[kr][c4 + 2] = v.z; T[kr][c4 + 3] = v.w;
    }
    __syncthreads();
    const int c   = tid >> 2;
    const int kk0 = (tid & 3) * 16;
    __bf16* dst = dstBase + (size_t)(rowBase + c) * DMODEL + k0 + kk0;
    bf16x8 o0, o1;
#pragma unroll
    for (int j = 0; j < 8; j++) o0[j] = (__bf16)T[kk0 + j][c];
#pragma unroll
    for (int j = 0; j < 8; j++) o1[j] = (__bf16)T[kk0 + 8 + j][c];
    *(bf16x8*)dst = o0;
    *(bf16x8*)(dst + 8) = o1;
}

// ---------------------------------------------------------------------------
// Stage 1: MFMA GEMM  x[8192x512]fp32 @ Wt^T -> Qt, Vt bf16 dim-major.
// ---------------------------------------------------------------------------
__global__ __launch_bounds__(256) void gemm_qv_mfma(
    const float* __restrict__ x,
    const __bf16* __restrict__ Wt,
    __bf16* __restrict__ Qt,
    __bf16* __restrict__ Vt)
{
    __shared__ __align__(16) __bf16 As[128 * 32];
    __shared__ __align__(16) __bf16 Bs[128 * 32];

    const int tid  = threadIdx.x;
    const int w    = tid >> 6;
    const int lane = tid & 63;
    const int lm   = lane & 15;
    const int q    = lane >> 4;
    const int wm   = w >> 1, wn = w & 1;
    const int row0 = blockIdx.y * 128;
    const int col0 = blockIdx.x * 128;

    const int asr = tid >> 3;          // 0..31 row within pass
    const int asc = (tid & 7) * 4;     // k float offset
    const float* gA = x + (size_t)(row0 + asr) * DMODEL + asc;

    const int sr = lane >> 2;
    const int sc = (lane & 3) * 8;
    const __bf16* gB0 = Wt + (size_t)(col0 + w * 32 +  0 + sr) * DMODEL + sc;
    const __bf16* gB1 = Wt + (size_t)(col0 + w * 32 + 16 + sr) * DMODEL + sc;
    __bf16* lB0 = Bs + (w * 32 +  0) * 32;
    __bf16* lB1 = Bs + (w * 32 + 16) * 32;

    f32x4 acc[4][4];
#pragma unroll
    for (int i = 0; i < 4; i++)
#pragma unroll
        for (int j = 0; j < 4; j++) acc[i][j] = (f32x4){0.f, 0.f, 0.f, 0.f};

    for (int k0 = 0; k0 < DMODEL; k0 += 32) {
        float4 a[4];
#pragma unroll
        for (int p = 0; p < 4; p++)
            a[p] = *(const float4*)(gA + (size_t)p * 32 * DMODEL);
        gA += 32;

        __syncthreads();
#pragma unroll
        for (int p = 0; p < 4; p++) {
            bf16x4 o;
            o[0] = (__bf16)a[p].x; o[1] = (__bf16)a[p].y;
            o[2] = (__bf16)a[p].z; o[3] = (__bf16)a[p].w;
            *(bf16x4*)&As[(asr + p * 32) * 32 + asc] = o;
        }
        GLOAD_LDS16(gB0, lB0); GLOAD_LDS16(gB1, lB1);
        gB0 += 32; gB1 += 32;
        __syncthreads();

        bf16x8 af[4], bfr[4];
#pragma unroll
        for (int mi = 0; mi < 4; mi++)
            af[mi] = *(const bf16x8*)&As[(wm * 64 + mi * 16 + lm) * 32 + q * 8];
#pragma unroll
        for (int ni = 0; ni < 4; ni++)
            bfr[ni] = *(const bf16x8*)&Bs[(wn * 64 + ni * 16 + lm) * 32 + q * 8];
#pragma unroll
        for (int mi = 0; mi < 4; mi++)
#pragma unroll
            for (int ni = 0; ni < 4; ni++)
                acc[mi][ni] = __builtin_amdgcn_mfma_f32_16x16x32_bf16(
                    af[mi], bfr[ni], acc[mi][ni], 0, 0, 0);
    }

#pragma unroll
    for (int ni = 0; ni < 4; ni++) {
        const int c  = col0 + wn * 64 + ni * 16 + lm;
        const int cc = c & 511;
        __bf16* outB = (c < 512 ? Qt : Vt);
#pragma unroll
        for (int mi = 0; mi < 4; mi++) {
            const int m  = row0 + wm * 64 + mi * 16 + q * 4;
            const int bb = m >> 12;
            const int nt = m & (N_TOK - 1);
            bf16x4 o;
            o[0] = (__bf16)acc[mi][ni][0];
            o[1] = (__bf16)acc[mi][ni][1];
            o[2] = (__bf16)acc[mi][ni][2];
            o[3] = (__bf16)acc[mi][ni][3];
            *(bf16x4*)(outB + ((size_t)(bb * 512 + cc)) * N_TOK + nt) = o;
        }
    }
}

// ---------------------------------------------------------------------------
// Stage 2: banded attention, LDS-staged V band from bf16 Vt.
// HALO FIX (round-7 failure): tok0 = i0-16 so every 8-token staging chunk is
// 8-aligned (i0 is 64-aligned). A clamped chunk is then ALWAYS fully outside
// the valid tap range (tokens -16..-1 / 4096..4111 are whole chunks), so
// clamp-shifted data only lands in weight-0 slots. Round 7's tok0=i0-12 made
// chunk [-4..3] mix invalid+valid -> boundary corruption (absmax 4.2e-6).
// Slots: token j -> slot j-i0+16; taps use slots 6..89 of 96.
// ---------------------------------------------------------------------------
#define VSTRIDE 97
__global__ __launch_bounds__(256) void attn_band(
    const __bf16* __restrict__ Qt,
    const __bf16* __restrict__ Vt,
    __bf16* __restrict__ Hb16)
{
    __shared__ float Vs[64 * VSTRIDE];   // 24,832 B

    const int tid  = threadIdx.x;
    const int bh   = blockIdx.x >> 6;
    const int tile = blockIdx.x & 63;
    const int i0   = tile * 64;
    const int b    = bh >> 3;
    const int h    = bh & 7;

    // stage V band: 64 dims x 96 token slots, 8-token bf16x8 chunks
    const __bf16* vband = Vt + (size_t)bh * DHEAD * N_TOK;
    const int tok0 = i0 - 16;
#pragma unroll
    for (int it = 0; it < 3; it++) {
        const int idx = it * 256 + tid;        // 0..767
        const int k   = idx / 12;              // dim
        const int s8  = idx - k * 12;          // 8-token chunk, 8-aligned
        const int tokg = tok0 + s8 * 8;
        const int tokc = min(max(tokg, 0), N_TOK - 8);
        const bf16x8 v = *(const bf16x8*)(vband + (size_t)k * N_TOK + tokc);
        float* dst = &Vs[k * VSTRIDE + s8 * 8];
#pragma unroll
        for (int e = 0; e < 8; e++) dst[e] = (float)v[e];
    }

    const int lane = tid & 63;
    const int wv   = tid >> 6;
    const int il   = lane & 15;
    const int p    = lane >> 4;
    const int i    = i0 + wv * 16 + il;
    const int slot0 = wv * 16 + il + 6;        // slot of tap d=0 (j=i-10)

    const __bf16* qbase = Qt + ((size_t)bh * DHEAD + p * 16) * N_TOK;
    float qv[16];
#pragma unroll
    for (int k = 0; k < 16; k++) qv[k] = (float)qbase[(size_t)k * N_TOK + i];

    __syncthreads();

    float c[16];
#pragma unroll
    for (int k = 0; k < 16; k++) c[k] = 0.f;
    float Z = 0.f;

#pragma unroll 3
    for (int d = 0; d < 2 * CTX + 1; d++) {
        const float* vrow = &Vs[p * 16 * VSTRIDE + slot0 + d];
        float v[16];
#pragma unroll
        for (int k = 0; k < 16; k++) v[k] = vrow[k * VSTRIDE];
        float s = 0.f;
#pragma unroll
        for (int k = 0; k < 16; k++) s += qv[k] * v[k];
        s += __shfl_xor(s, 16, 64);
        s += __shfl_xor(s, 32, 64);

        const int j = i + d - CTX;
        const bool valid = (d != CTX) && (j >= 0) && (j < N_TOK);
        const float w = valid ? __expf(s * 0.0625f) : 0.f;
        Z += w;
#pragma unroll
        for (int k = 0; k < 16; k++) c[k] += w * v[k];
    }

    const float inv = 1.f / Z;
    __bf16* dst = Hb16 + ((size_t)(b * N_TOK + i)) * DMODEL + h * DHEAD + p * 16;
    bf16x8 o0, o1;
#pragma unroll
    for (int k = 0; k < 8; k++) o0[k] = (__bf16)(c[k] * inv);
#pragma unroll
    for (int k = 0; k < 8; k++) o1[k] = (__bf16)(c[8 + k] * inv);
    *(bf16x8*)dst = o0;
    *(bf16x8*)(dst + 8) = o1;
}

// ---------------------------------------------------------------------------
// Stage 3: MFMA GEMM  Hb16[8192x512] @ Wup -> out fp32 [8192x512].
// ---------------------------------------------------------------------------
__global__ __launch_bounds__(256) void gemm_out_mfma(
    const __bf16* __restrict__ Hb,
    const __bf16* __restrict__ Wt,
    float* __restrict__ out)
{
    __shared__ __align__(16) __bf16 As[128 * 32];
    __shared__ __align__(16) __bf16 Bs[64 * 32];

    const int tid  = threadIdx.x;
    const int w    = tid >> 6;
    const int lane = tid & 63;
    const int lm   = lane & 15;
    const int q    = lane >> 4;
    const int row0 = blockIdx.y * 128;
    const int col0 = blockIdx.x * 64;

    const int sr = lane >> 2;
    const int sc = (lane & 3) * 8;
    const __bf16* gA0 = Hb + (size_t)(row0 + w * 32 +  0 + sr) * DMODEL + sc;
    const __bf16* gA1 = Hb + (size_t)(row0 + w * 32 + 16 + sr) * DMODEL + sc;
    const __bf16* gB0 = Wt + (size_t)(col0 + w * 16 + sr) * DMODEL + sc;
    __bf16* lA0 = As + (w * 32 +  0) * 32;
    __bf16* lA1 = As + (w * 32 + 16) * 32;
    __bf16* lB0 = Bs + (w * 16) * 32;

    f32x4 acc[2][4];
#pragma unroll
    for (int i = 0; i < 2; i++)
#pragma unroll
        for (int j = 0; j < 4; j++) acc[i][j] = (f32x4){0.f, 0.f, 0.f, 0.f};

    for (int k0 = 0; k0 < DMODEL; k0 += 32) {
        __syncthreads();
        GLOAD_LDS16(gA0, lA0); GLOAD_LDS16(gA1, lA1); GLOAD_LDS16(gB0, lB0);
        gA0 += 32; gA1 += 32; gB0 += 32;
        __syncthreads();

        bf16x8 af[2], bfr[4];
#pragma unroll
        for (int mi = 0; mi < 2; mi++)
            af[mi] = *(const bf16x8*)&As[(w * 32 + mi * 16 + lm) * 32 + q * 8];
#pragma unroll
        for (int ni = 0; ni < 4; ni++)
            bfr[ni] = *(const bf16x8*)&Bs[(ni * 16 + lm) * 32 + q * 8];
#pragma unroll
        for (int mi = 0; mi < 2; mi++)
#pragma unroll
            for (int ni = 0; ni < 4; ni++)
                acc[mi][ni] = __builtin_amdgcn_mfma_f32_16x16x32_bf16(
                    af[mi], bfr[ni], acc[mi][ni], 0, 0, 0);
    }

#pragma unroll
    for (int mi = 0; mi < 2; mi++) {
        const int m0 = row0 + w * 32 + mi * 16 + q * 4;
#pragma unroll
        for (int ni = 0; ni < 4; ni++) {
            const int n = col0 + ni * 16 + lm;
#pragma unroll
            for (int r = 0; r < 4; r++)
                out[(size_t)(m0 + r) * DMODEL + n] = acc[mi][ni][r];
        }
    }
}

// ---------------------------------------------------------------------------
extern "C" void kernel_launch(void* const* d_in, const int* in_sizes, int n_in,
                              void* d_out, int out_size, void* d_ws, size_t ws_size,
                              hipStream_t stream)
{
    const float* x   = (const float*)d_in[0];
    const float* Wq  = (const float*)d_in[1];
    const float* Wv  = (const float*)d_in[2];
    const float* Wup = (const float*)d_in[3];
    float* out = (float*)d_out;

    const size_t QV = (size_t)2 * NHEAD * N_TOK * DHEAD;   // 4,194,304 elems
    __bf16* Qt   = (__bf16*)d_ws;                          // 8.39 MB
    __bf16* Vt   = Qt + QV;                                // 8.39 MB
    __bf16* Hb16 = Vt + QV;                                // 8.39 MB
    __bf16* Wtqv = Hb16 + (size_t)NROW * DMODEL;           // 1.05 MB
    __bf16* Wtup = Wtqv + (size_t)1024 * DMODEL;           // 0.52 MB

    dim3 blk(256);
    conv_w       <<<dim3(192),   blk, 0, stream>>>(Wq, Wv, Wup, Wtqv, Wtup);
    gemm_qv_mfma <<<dim3(8, 64), blk, 0, stream>>>(x, Wtqv, Qt, Vt);
    attn_band    <<<dim3(1024),  blk, 0, stream>>>(Qt, Vt, Hb16);
    gemm_out_mfma<<<dim3(8, 64), blk, 0, stream>>>(Hb16, Wtup, out);
}

// Round 9
// 119.486 us; speedup vs baseline: 3.5719x; 1.0450x over previous
//
#include <hip/hip_runtime.h>
#include <math.h>

#define N_TOK 4096
#define DMODEL 512
#define NHEAD 8
#define DHEAD 64
#define CTX 10
#define NROW 8192  // B * N_TOK

typedef __bf16 bf16x4 __attribute__((ext_vector_type(4)));
typedef __bf16 bf16x8 __attribute__((ext_vector_type(8)));
typedef float  f32x4  __attribute__((ext_vector_type(4)));

#define GLOAD_LDS16(g, l) __builtin_amdgcn_global_load_lds(                 \
    (const __attribute__((address_space(1))) void*)(g),                     \
    (__attribute__((address_space(3))) void*)(l), 16, 0, 0)

// ---------------------------------------------------------------------------
// Merged weight transpose-convert:
//   blocks [0,128):  Wq|Wv [h][k=512][kk=64] fp32 -> Wtqv[n=1024][k=512] bf16
//   blocks [128,192): Wup [k=512][n=512] fp32     -> Wtup[n=512][k=512] bf16
// ---------------------------------------------------------------------------
__global__ __launch_bounds__(256) void conv_w(const float* __restrict__ Wq,
                                              const float* __restrict__ Wv,
                                              const float* __restrict__ Wup,
                                              __bf16* __restrict__ Wtqv,
                                              __bf16* __restrict__ Wtup)
{
    __shared__ float T[64][65];
    const int tid = threadIdx.x;
    const int bid = blockIdx.x;

    const float* src;
    __bf16* dstBase;
    int k0, rowBase, srcStride;
    if (bid < 128) {
        k0 = (bid & 7) * 64;
        const int h   = (bid >> 3) & 7;
        const int mat = bid >> 6;
        src = (mat ? Wv : Wq) + (size_t)h * DMODEL * DHEAD;
        dstBase = Wtqv;
        rowBase = mat * 512 + h * 64;
        srcStride = DHEAD;
    } else {
        const int b2 = bid - 128;
        k0 = (b2 & 7) * 64;
        const int n0 = (b2 >> 3) * 64;
        src = Wup + n0;
        dstBase = Wtup;
        rowBase = n0;
        srcStride = DMODEL;
    }

#pragma unroll
    for (int it = 0; it < 4; it++) {
        const int kr = it * 16 + (tid >> 4);
        const int c4 = (tid & 15) * 4;
        const float4 v = *(const float4*)(src + (size_t)(k0 + kr) * srcStride + c4);
        T[kr][c4 + 0] = v.x; T[kr][c4 + 1] = v.y;
        T[kr][c4 + 2] = v.z; T[kr][c4 + 3] = v.w;
    }
    __syncthreads();
    const int c   = tid >> 2;
    const int kk0 = (tid & 3) * 16;
    __bf16* dst = dstBase + (size_t)(rowBase + c) * DMODEL + k0 + kk0;
    bf16x8 o0, o1;
#pragma unroll
    for (int j = 0; j < 8; j++) o0[j] = (__bf16)T[kk0 + j][c];
#pragma unroll
    for (int j = 0; j < 8; j++) o1[j] = (__bf16)T[kk0 + 8 + j][c];
    *(bf16x8*)dst = o0;
    *(bf16x8*)(dst + 8) = o1;
}

// ---------------------------------------------------------------------------
// Stage 1: MFMA GEMM  x[8192x512]fp32 @ Wt^T -> Qt, Vt bf16 dim-major.
// XCD swizzle: 1-D grid 512; row = bid & 63, col = bid >> 6. The 8 blocks
// sharing x row-tile r are {r, 64+r, ..} == r (mod 8) -> same XCD, so each
// row-tile is HBM-fetched once and L2-served 7 times (was: 8 XCDs x 33.6 MB
// = 268 MB of L2-miss flow). All 512 blocks co-resident at 2/CU.
// ---------------------------------------------------------------------------
__global__ __launch_bounds__(256) void gemm_qv_mfma(
    const float* __restrict__ x,
    const __bf16* __restrict__ Wt,
    __bf16* __restrict__ Qt,
    __bf16* __restrict__ Vt)
{
    __shared__ __align__(16) __bf16 As[128 * 32];
    __shared__ __align__(16) __bf16 Bs[128 * 32];

    const int tid  = threadIdx.x;
    const int w    = tid >> 6;
    const int lane = tid & 63;
    const int lm   = lane & 15;
    const int q    = lane >> 4;
    const int wm   = w >> 1, wn = w & 1;
    const int bid  = blockIdx.x;
    const int row0 = (bid & 63) * 128;     // XCD-swizzled (see header comment)
    const int col0 = (bid >> 6) * 128;

    const int asr = tid >> 3;          // 0..31 row within pass
    const int asc = (tid & 7) * 4;     // k float offset
    const float* gA = x + (size_t)(row0 + asr) * DMODEL + asc;

    const int sr = lane >> 2;
    const int sc = (lane & 3) * 8;
    const __bf16* gB0 = Wt + (size_t)(col0 + w * 32 +  0 + sr) * DMODEL + sc;
    const __bf16* gB1 = Wt + (size_t)(col0 + w * 32 + 16 + sr) * DMODEL + sc;
    __bf16* lB0 = Bs + (w * 32 +  0) * 32;
    __bf16* lB1 = Bs + (w * 32 + 16) * 32;

    f32x4 acc[4][4];
#pragma unroll
    for (int i = 0; i < 4; i++)
#pragma unroll
        for (int j = 0; j < 4; j++) acc[i][j] = (f32x4){0.f, 0.f, 0.f, 0.f};

    for (int k0 = 0; k0 < DMODEL; k0 += 32) {
        float4 a[4];
#pragma unroll
        for (int p = 0; p < 4; p++)
            a[p] = *(const float4*)(gA + (size_t)p * 32 * DMODEL);
        gA += 32;

        __syncthreads();
#pragma unroll
        for (int p = 0; p < 4; p++) {
            bf16x4 o;
            o[0] = (__bf16)a[p].x; o[1] = (__bf16)a[p].y;
            o[2] = (__bf16)a[p].z; o[3] = (__bf16)a[p].w;
            *(bf16x4*)&As[(asr + p * 32) * 32 + asc] = o;
        }
        GLOAD_LDS16(gB0, lB0); GLOAD_LDS16(gB1, lB1);
        gB0 += 32; gB1 += 32;
        __syncthreads();

        bf16x8 af[4], bfr[4];
#pragma unroll
        for (int mi = 0; mi < 4; mi++)
            af[mi] = *(const bf16x8*)&As[(wm * 64 + mi * 16 + lm) * 32 + q * 8];
#pragma unroll
        for (int ni = 0; ni < 4; ni++)
            bfr[ni] = *(const bf16x8*)&Bs[(wn * 64 + ni * 16 + lm) * 32 + q * 8];
#pragma unroll
        for (int mi = 0; mi < 4; mi++)
#pragma unroll
            for (int ni = 0; ni < 4; ni++)
                acc[mi][ni] = __builtin_amdgcn_mfma_f32_16x16x32_bf16(
                    af[mi], bfr[ni], acc[mi][ni], 0, 0, 0);
    }

#pragma unroll
    for (int ni = 0; ni < 4; ni++) {
        const int c  = col0 + wn * 64 + ni * 16 + lm;
        const int cc = c & 511;
        __bf16* outB = (c < 512 ? Qt : Vt);
#pragma unroll
        for (int mi = 0; mi < 4; mi++) {
            const int m  = row0 + wm * 64 + mi * 16 + q * 4;
            const int bb = m >> 12;
            const int nt = m & (N_TOK - 1);
            bf16x4 o;
            o[0] = (__bf16)acc[mi][ni][0];
            o[1] = (__bf16)acc[mi][ni][1];
            o[2] = (__bf16)acc[mi][ni][2];
            o[3] = (__bf16)acc[mi][ni][3];
            *(bf16x4*)(outB + ((size_t)(bb * 512 + cc)) * N_TOK + nt) = o;
        }
    }
}

// ---------------------------------------------------------------------------
// Stage 2: banded attention, LDS-staged V band from bf16 Vt (round-8 form:
// 8-aligned halo tok0 = i0-16 so clamped chunks are fully-invalid only).
// ---------------------------------------------------------------------------
#define VSTRIDE 97
__global__ __launch_bounds__(256) void attn_band(
    const __bf16* __restrict__ Qt,
    const __bf16* __restrict__ Vt,
    __bf16* __restrict__ Hb16)
{
    __shared__ float Vs[64 * VSTRIDE];   // 24,832 B

    const int tid  = threadIdx.x;
    const int bh   = blockIdx.x >> 6;
    const int tile = blockIdx.x & 63;
    const int i0   = tile * 64;
    const int b    = bh >> 3;
    const int h    = bh & 7;

    const __bf16* vband = Vt + (size_t)bh * DHEAD * N_TOK;
    const int tok0 = i0 - 16;
#pragma unroll
    for (int it = 0; it < 3; it++) {
        const int idx = it * 256 + tid;        // 0..767
        const int k   = idx / 12;              // dim
        const int s8  = idx - k * 12;          // 8-token chunk, 8-aligned
        const int tokg = tok0 + s8 * 8;
        const int tokc = min(max(tokg, 0), N_TOK - 8);
        const bf16x8 v = *(const bf16x8*)(vband + (size_t)k * N_TOK + tokc);
        float* dst = &Vs[k * VSTRIDE + s8 * 8];
#pragma unroll
        for (int e = 0; e < 8; e++) dst[e] = (float)v[e];
    }

    const int lane = tid & 63;
    const int wv   = tid >> 6;
    const int il   = lane & 15;
    const int p    = lane >> 4;
    const int i    = i0 + wv * 16 + il;
    const int slot0 = wv * 16 + il + 6;        // slot of tap d=0 (j=i-10)

    const __bf16* qbase = Qt + ((size_t)bh * DHEAD + p * 16) * N_TOK;
    float qv[16];
#pragma unroll
    for (int k = 0; k < 16; k++) qv[k] = (float)qbase[(size_t)k * N_TOK + i];

    __syncthreads();

    float c[16];
#pragma unroll
    for (int k = 0; k < 16; k++) c[k] = 0.f;
    float Z = 0.f;

#pragma unroll 3
    for (int d = 0; d < 2 * CTX + 1; d++) {
        const float* vrow = &Vs[p * 16 * VSTRIDE + slot0 + d];
        float v[16];
#pragma unroll
        for (int k = 0; k < 16; k++) v[k] = vrow[k * VSTRIDE];
        float s = 0.f;
#pragma unroll
        for (int k = 0; k < 16; k++) s += qv[k] * v[k];
        s += __shfl_xor(s, 16, 64);
        s += __shfl_xor(s, 32, 64);

        const int j = i + d - CTX;
        const bool valid = (d != CTX) && (j >= 0) && (j < N_TOK);
        const float w = valid ? __expf(s * 0.0625f) : 0.f;
        Z += w;
#pragma unroll
        for (int k = 0; k < 16; k++) c[k] += w * v[k];
    }

    const float inv = 1.f / Z;
    __bf16* dst = Hb16 + ((size_t)(b * N_TOK + i)) * DMODEL + h * DHEAD + p * 16;
    bf16x8 o0, o1;
#pragma unroll
    for (int k = 0; k < 8; k++) o0[k] = (__bf16)(c[k] * inv);
#pragma unroll
    for (int k = 0; k < 8; k++) o1[k] = (__bf16)(c[8 + k] * inv);
    *(bf16x8*)dst = o0;
    *(bf16x8*)(dst + 8) = o1;
}

// ---------------------------------------------------------------------------
// Stage 3: MFMA GEMM  Hb16[8192x512] @ Wup -> out fp32 [8192x512].
// Same XCD swizzle: row = bid & 63, col = bid >> 6 (8 col-tiles of 64).
// ---------------------------------------------------------------------------
__global__ __launch_bounds__(256) void gemm_out_mfma(
    const __bf16* __restrict__ Hb,
    const __bf16* __restrict__ Wt,
    float* __restrict__ out)
{
    __shared__ __align__(16) __bf16 As[128 * 32];
    __shared__ __align__(16) __bf16 Bs[64 * 32];

    const int tid  = threadIdx.x;
    const int w    = tid >> 6;
    const int lane = tid & 63;
    const int lm   = lane & 15;
    const int q    = lane >> 4;
    const int bid  = blockIdx.x;
    const int row0 = (bid & 63) * 128;     // XCD-swizzled
    const int col0 = (bid >> 6) * 64;

    const int sr = lane >> 2;
    const int sc = (lane & 3) * 8;
    const __bf16* gA0 = Hb + (size_t)(row0 + w * 32 +  0 + sr) * DMODEL + sc;
    const __bf16* gA1 = Hb + (size_t)(row0 + w * 32 + 16 + sr) * DMODEL + sc;
    const __bf16* gB0 = Wt + (size_t)(col0 + w * 16 + sr) * DMODEL + sc;
    __bf16* lA0 = As + (w * 32 +  0) * 32;
    __bf16* lA1 = As + (w * 32 + 16) * 32;
    __bf16* lB0 = Bs + (w * 16) * 32;

    f32x4 acc[2][4];
#pragma unroll
    for (int i = 0; i < 2; i++)
#pragma unroll
        for (int j = 0; j < 4; j++) acc[i][j] = (f32x4){0.f, 0.f, 0.f, 0.f};

    for (int k0 = 0; k0 < DMODEL; k0 += 32) {
        __syncthreads();
        GLOAD_LDS16(gA0, lA0); GLOAD_LDS16(gA1, lA1); GLOAD_LDS16(gB0, lB0);
        gA0 += 32; gA1 += 32; gB0 += 32;
        __syncthreads();

        bf16x8 af[2], bfr[4];
#pragma unroll
        for (int mi = 0; mi < 2; mi++)
            af[mi] = *(const bf16x8*)&As[(w * 32 + mi * 16 + lm) * 32 + q * 8];
#pragma unroll
        for (int ni = 0; ni < 4; ni++)
            bfr[ni] = *(const bf16x8*)&Bs[(ni * 16 + lm) * 32 + q * 8];
#pragma unroll
        for (int mi = 0; mi < 2; mi++)
#pragma unroll
            for (int ni = 0; ni < 4; ni++)
                acc[mi][ni] = __builtin_amdgcn_mfma_f32_16x16x32_bf16(
                    af[mi], bfr[ni], acc[mi][ni], 0, 0, 0);
    }

#pragma unroll
    for (int mi = 0; mi < 2; mi++) {
        const int m0 = row0 + w * 32 + mi * 16 + q * 4;
#pragma unroll
        for (int ni = 0; ni < 4; ni++) {
            const int n = col0 + ni * 16 + lm;
#pragma unroll
            for (int r = 0; r < 4; r++)
                out[(size_t)(m0 + r) * DMODEL + n] = acc[mi][ni][r];
        }
    }
}

// ---------------------------------------------------------------------------
extern "C" void kernel_launch(void* const* d_in, const int* in_sizes, int n_in,
                              void* d_out, int out_size, void* d_ws, size_t ws_size,
                              hipStream_t stream)
{
    const float* x   = (const float*)d_in[0];
    const float* Wq  = (const float*)d_in[1];
    const float* Wv  = (const float*)d_in[2];
    const float* Wup = (const float*)d_in[3];
    float* out = (float*)d_out;

    const size_t QV = (size_t)2 * NHEAD * N_TOK * DHEAD;   // 4,194,304 elems
    __bf16* Qt   = (__bf16*)d_ws;                          // 8.39 MB
    __bf16* Vt   = Qt + QV;                                // 8.39 MB
    __bf16* Hb16 = Vt + QV;                                // 8.39 MB
    __bf16* Wtqv = Hb16 + (size_t)NROW * DMODEL;           // 1.05 MB
    __bf16* Wtup = Wtqv + (size_t)1024 * DMODEL;           // 0.52 MB

    dim3 blk(256);
    conv_w       <<<dim3(192),  blk, 0, stream>>>(Wq, Wv, Wup, Wtqv, Wtup);
    gemm_qv_mfma <<<dim3(512),  blk, 0, stream>>>(x, Wtqv, Qt, Vt);
    attn_band    <<<dim3(1024), blk, 0, stream>>>(Qt, Vt, Hb16);
    gemm_out_mfma<<<dim3(512),  blk, 0, stream>>>(Hb16, Wtup, out);
}

// Round 10
// 118.793 us; speedup vs baseline: 3.5928x; 1.0058x over previous
//
#include <hip/hip_runtime.h>
#include <math.h>

#define N_TOK 4096
#define DMODEL 512
#define NHEAD 8
#define DHEAD 64
#define CTX 10
#define NROW 8192  // B * N_TOK

typedef __bf16 bf16x4 __attribute__((ext_vector_type(4)));
typedef __bf16 bf16x8 __attribute__((ext_vector_type(8)));
typedef float  f32x4  __attribute__((ext_vector_type(4)));

#define GLOAD_LDS16(g, l) __builtin_amdgcn_global_load_lds(                 \
    (const __attribute__((address_space(1))) void*)(g),                     \
    (__attribute__((address_space(3))) void*)(l), 16, 0, 0)

// ---------------------------------------------------------------------------
// Merged weight transpose-convert:
//   blocks [0,128):  Wq|Wv [h][k=512][kk=64] fp32 -> Wtqv[n=1024][k=512] bf16
//   blocks [128,192): Wup [k=512][n=512] fp32     -> Wtup[n=512][k=512] bf16
// ---------------------------------------------------------------------------
__global__ __launch_bounds__(256) void conv_w(const float* __restrict__ Wq,
                                              const float* __restrict__ Wv,
                                              const float* __restrict__ Wup,
                                              __bf16* __restrict__ Wtqv,
                                              __bf16* __restrict__ Wtup)
{
    __shared__ float T[64][65];
    const int tid = threadIdx.x;
    const int bid = blockIdx.x;

    const float* src;
    __bf16* dstBase;
    int k0, rowBase, srcStride;
    if (bid < 128) {
        k0 = (bid & 7) * 64;
        const int h   = (bid >> 3) & 7;
        const int mat = bid >> 6;
        src = (mat ? Wv : Wq) + (size_t)h * DMODEL * DHEAD;
        dstBase = Wtqv;
        rowBase = mat * 512 + h * 64;
        srcStride = DHEAD;
    } else {
        const int b2 = bid - 128;
        k0 = (b2 & 7) * 64;
        const int n0 = (b2 >> 3) * 64;
        src = Wup + n0;
        dstBase = Wtup;
        rowBase = n0;
        srcStride = DMODEL;
    }

#pragma unroll
    for (int it = 0; it < 4; it++) {
        const int kr = it * 16 + (tid >> 4);
        const int c4 = (tid & 15) * 4;
        const float4 v = *(const float4*)(src + (size_t)(k0 + kr) * srcStride + c4);
        T[kr][c4 + 0] = v.x; T[kr][c4 + 1] = v.y;
        T[kr][c4 + 2] = v.z; T[kr][c4 + 3] = v.w;
    }
    __syncthreads();
    const int c   = tid >> 2;
    const int kk0 = (tid & 3) * 16;
    __bf16* dst = dstBase + (size_t)(rowBase + c) * DMODEL + k0 + kk0;
    bf16x8 o0, o1;
#pragma unroll
    for (int j = 0; j < 8; j++) o0[j] = (__bf16)T[kk0 + j][c];
#pragma unroll
    for (int j = 0; j < 8; j++) o1[j] = (__bf16)T[kk0 + 8 + j][c];
    *(bf16x8*)dst = o0;
    *(bf16x8*)(dst + 8) = o1;
}

// ---------------------------------------------------------------------------
// Stage 1: MFMA GEMM  x[8192x512]fp32 @ Wt^T -> Qt, Vt bf16 dim-major.
// Round-10 change: 128x64 tile, grid 1024 -> 4 blocks/CU (was 128x128,
// grid 512, 2/CU). The 16-iter K-loop is barrier-drain bound; doubling
// resident blocks gives other waves to run through each drain (m114).
// XCD swizzle preserved: row = bid & 63 (64 == 0 mod 8 -> all 16 col-blocks
// of a row-tile land on one XCD; per-XCD set 512 KB x + 1 MB Wtqv in L2).
// ---------------------------------------------------------------------------
__global__ __launch_bounds__(256) void gemm_qv_mfma(
    const float* __restrict__ x,
    const __bf16* __restrict__ Wt,
    __bf16* __restrict__ Qt,
    __bf16* __restrict__ Vt)
{
    __shared__ __align__(16) __bf16 As[128 * 32];
    __shared__ __align__(16) __bf16 Bs[64 * 32];

    const int tid  = threadIdx.x;
    const int w    = tid >> 6;
    const int lane = tid & 63;
    const int lm   = lane & 15;
    const int q    = lane >> 4;
    const int bid  = blockIdx.x;
    const int row0 = (bid & 63) * 128;     // XCD-swizzled
    const int col0 = (bid >> 6) * 64;      // 16 col-tiles

    const int asr = tid >> 3;          // 0..31 row within pass
    const int asc = (tid & 7) * 4;     // k float offset
    const float* gA = x + (size_t)(row0 + asr) * DMODEL + asc;

    const int sr = lane >> 2;          // 0..15
    const int sc = (lane & 3) * 8;
    const __bf16* gB0 = Wt + (size_t)(col0 + w * 16 + sr) * DMODEL + sc;
    __bf16* lB0 = Bs + (w * 16) * 32;

    f32x4 acc[2][4];
#pragma unroll
    for (int i = 0; i < 2; i++)
#pragma unroll
        for (int j = 0; j < 4; j++) acc[i][j] = (f32x4){0.f, 0.f, 0.f, 0.f};

    for (int k0 = 0; k0 < DMODEL; k0 += 32) {
        float4 a[4];
#pragma unroll
        for (int p = 0; p < 4; p++)
            a[p] = *(const float4*)(gA + (size_t)p * 32 * DMODEL);
        gA += 32;

        __syncthreads();
#pragma unroll
        for (int p = 0; p < 4; p++) {
            bf16x4 o;
            o[0] = (__bf16)a[p].x; o[1] = (__bf16)a[p].y;
            o[2] = (__bf16)a[p].z; o[3] = (__bf16)a[p].w;
            *(bf16x4*)&As[(asr + p * 32) * 32 + asc] = o;
        }
        GLOAD_LDS16(gB0, lB0);
        gB0 += 32;
        __syncthreads();

        bf16x8 af[2], bfr[4];
#pragma unroll
        for (int mi = 0; mi < 2; mi++)
            af[mi] = *(const bf16x8*)&As[(w * 32 + mi * 16 + lm) * 32 + q * 8];
#pragma unroll
        for (int ni = 0; ni < 4; ni++)
            bfr[ni] = *(const bf16x8*)&Bs[(ni * 16 + lm) * 32 + q * 8];
#pragma unroll
        for (int mi = 0; mi < 2; mi++)
#pragma unroll
            for (int ni = 0; ni < 4; ni++)
                acc[mi][ni] = __builtin_amdgcn_mfma_f32_16x16x32_bf16(
                    af[mi], bfr[ni], acc[mi][ni], 0, 0, 0);
    }

    // Epilogue: bf16 dim-major scatter [bb*512+cc][token]
#pragma unroll
    for (int ni = 0; ni < 4; ni++) {
        const int c  = col0 + ni * 16 + lm;
        const int cc = c & 511;
        __bf16* outB = (c < 512 ? Qt : Vt);
#pragma unroll
        for (int mi = 0; mi < 2; mi++) {
            const int m  = row0 + w * 32 + mi * 16 + q * 4;
            const int bb = m >> 12;
            const int nt = m & (N_TOK - 1);
            bf16x4 o;
            o[0] = (__bf16)acc[mi][ni][0];
            o[1] = (__bf16)acc[mi][ni][1];
            o[2] = (__bf16)acc[mi][ni][2];
            o[3] = (__bf16)acc[mi][ni][3];
            *(bf16x4*)(outB + ((size_t)(bb * 512 + cc)) * N_TOK + nt) = o;
        }
    }
}

// ---------------------------------------------------------------------------
// Stage 2: banded attention, LDS-staged V band from bf16 Vt (round-8 form:
// 8-aligned halo tok0 = i0-16 so clamped chunks are fully-invalid only).
// ---------------------------------------------------------------------------
#define VSTRIDE 97
__global__ __launch_bounds__(256) void attn_band(
    const __bf16* __restrict__ Qt,
    const __bf16* __restrict__ Vt,
    __bf16* __restrict__ Hb16)
{
    __shared__ float Vs[64 * VSTRIDE];   // 24,832 B

    const int tid  = threadIdx.x;
    const int bh   = blockIdx.x >> 6;
    const int tile = blockIdx.x & 63;
    const int i0   = tile * 64;
    const int b    = bh >> 3;
    const int h    = bh & 7;

    const __bf16* vband = Vt + (size_t)bh * DHEAD * N_TOK;
    const int tok0 = i0 - 16;
#pragma unroll
    for (int it = 0; it < 3; it++) {
        const int idx = it * 256 + tid;        // 0..767
        const int k   = idx / 12;              // dim
        const int s8  = idx - k * 12;          // 8-token chunk, 8-aligned
        const int tokg = tok0 + s8 * 8;
        const int tokc = min(max(tokg, 0), N_TOK - 8);
        const bf16x8 v = *(const bf16x8*)(vband + (size_t)k * N_TOK + tokc);
        float* dst = &Vs[k * VSTRIDE + s8 * 8];
#pragma unroll
        for (int e = 0; e < 8; e++) dst[e] = (float)v[e];
    }

    const int lane = tid & 63;
    const int wv   = tid >> 6;
    const int il   = lane & 15;
    const int p    = lane >> 4;
    const int i    = i0 + wv * 16 + il;
    const int slot0 = wv * 16 + il + 6;        // slot of tap d=0 (j=i-10)

    const __bf16* qbase = Qt + ((size_t)bh * DHEAD + p * 16) * N_TOK;
    float qv[16];
#pragma unroll
    for (int k = 0; k < 16; k++) qv[k] = (float)qbase[(size_t)k * N_TOK + i];

    __syncthreads();

    float c[16];
#pragma unroll
    for (int k = 0; k < 16; k++) c[k] = 0.f;
    float Z = 0.f;

#pragma unroll 3
    for (int d = 0; d < 2 * CTX + 1; d++) {
        const float* vrow = &Vs[p * 16 * VSTRIDE + slot0 + d];
        float v[16];
#pragma unroll
        for (int k = 0; k < 16; k++) v[k] = vrow[k * VSTRIDE];
        float s = 0.f;
#pragma unroll
        for (int k = 0; k < 16; k++) s += qv[k] * v[k];
        s += __shfl_xor(s, 16, 64);
        s += __shfl_xor(s, 32, 64);

        const int j = i + d - CTX;
        const bool valid = (d != CTX) && (j >= 0) && (j < N_TOK);
        const float w = valid ? __expf(s * 0.0625f) : 0.f;
        Z += w;
#pragma unroll
        for (int k = 0; k < 16; k++) c[k] += w * v[k];
    }

    const float inv = 1.f / Z;
    __bf16* dst = Hb16 + ((size_t)(b * N_TOK + i)) * DMODEL + h * DHEAD + p * 16;
    bf16x8 o0, o1;
#pragma unroll
    for (int k = 0; k < 8; k++) o0[k] = (__bf16)(c[k] * inv);
#pragma unroll
    for (int k = 0; k < 8; k++) o1[k] = (__bf16)(c[8 + k] * inv);
    *(bf16x8*)dst = o0;
    *(bf16x8*)(dst + 8) = o1;
}

// ---------------------------------------------------------------------------
// Stage 3: MFMA GEMM  Hb16[8192x512] @ Wup -> out fp32 [8192x512].
// XCD swizzle: row = bid & 63, col = bid >> 6 (8 col-tiles of 64).
// ---------------------------------------------------------------------------
__global__ __launch_bounds__(256) void gemm_out_mfma(
    const __bf16* __restrict__ Hb,
    const __bf16* __restrict__ Wt,
    float* __restrict__ out)
{
    __shared__ __align__(16) __bf16 As[128 * 32];
    __shared__ __align__(16) __bf16 Bs[64 * 32];

    const int tid  = threadIdx.x;
    const int w    = tid >> 6;
    const int lane = tid & 63;
    const int lm   = lane & 15;
    const int q    = lane >> 4;
    const int bid  = blockIdx.x;
    const int row0 = (bid & 63) * 128;     // XCD-swizzled
    const int col0 = (bid >> 6) * 64;

    const int sr = lane >> 2;
    const int sc = (lane & 3) * 8;
    const __bf16* gA0 = Hb + (size_t)(row0 + w * 32 +  0 + sr) * DMODEL + sc;
    const __bf16* gA1 = Hb + (size_t)(row0 + w * 32 + 16 + sr) * DMODEL + sc;
    const __bf16* gB0 = Wt + (size_t)(col0 + w * 16 + sr) * DMODEL + sc;
    __bf16* lA0 = As + (w * 32 +  0) * 32;
    __bf16* lA1 = As + (w * 32 + 16) * 32;
    __bf16* lB0 = Bs + (w * 16) * 32;

    f32x4 acc[2][4];
#pragma unroll
    for (int i = 0; i < 2; i++)
#pragma unroll
        for (int j = 0; j < 4; j++) acc[i][j] = (f32x4){0.f, 0.f, 0.f, 0.f};

    for (int k0 = 0; k0 < DMODEL; k0 += 32) {
        __syncthreads();
        GLOAD_LDS16(gA0, lA0); GLOAD_LDS16(gA1, lA1); GLOAD_LDS16(gB0, lB0);
        gA0 += 32; gA1 += 32; gB0 += 32;
        __syncthreads();

        bf16x8 af[2], bfr[4];
#pragma unroll
        for (int mi = 0; mi < 2; mi++)
            af[mi] = *(const bf16x8*)&As[(w * 32 + mi * 16 + lm) * 32 + q * 8];
#pragma unroll
        for (int ni = 0; ni < 4; ni++)
            bfr[ni] = *(const bf16x8*)&Bs[(ni * 16 + lm) * 32 + q * 8];
#pragma unroll
        for (int mi = 0; mi < 2; mi++)
#pragma unroll
            for (int ni = 0; ni < 4; ni++)
                acc[mi][ni] = __builtin_amdgcn_mfma_f32_16x16x32_bf16(
                    af[mi], bfr[ni], acc[mi][ni], 0, 0, 0);
    }

#pragma unroll
    for (int mi = 0; mi < 2; mi++) {
        const int m0 = row0 + w * 32 + mi * 16 + q * 4;
#pragma unroll
        for (int ni = 0; ni < 4; ni++) {
            const int n = col0 + ni * 16 + lm;
#pragma unroll
            for (int r = 0; r < 4; r++)
                out[(size_t)(m0 + r) * DMODEL + n] = acc[mi][ni][r];
        }
    }
}

// ---------------------------------------------------------------------------
extern "C" void kernel_launch(void* const* d_in, const int* in_sizes, int n_in,
                              void* d_out, int out_size, void* d_ws, size_t ws_size,
                              hipStream_t stream)
{
    const float* x   = (const float*)d_in[0];
    const float* Wq  = (const float*)d_in[1];
    const float* Wv  = (const float*)d_in[2];
    const float* Wup = (const float*)d_in[3];
    float* out = (float*)d_out;

    const size_t QV = (size_t)2 * NHEAD * N_TOK * DHEAD;   // 4,194,304 elems
    __bf16* Qt   = (__bf16*)d_ws;                          // 8.39 MB
    __bf16* Vt   = Qt + QV;                                // 8.39 MB
    __bf16* Hb16 = Vt + QV;                                // 8.39 MB
    __bf16* Wtqv = Hb16 + (size_t)NROW * DMODEL;           // 1.05 MB
    __bf16* Wtup = Wtqv + (size_t)1024 * DMODEL;           // 0.52 MB

    dim3 blk(256);
    conv_w       <<<dim3(192),  blk, 0, stream>>>(Wq, Wv, Wup, Wtqv, Wtup);
    gemm_qv_mfma <<<dim3(1024), blk, 0, stream>>>(x, Wtqv, Qt, Vt);
    attn_band    <<<dim3(1024), blk, 0, stream>>>(Qt, Vt, Hb16);
    gemm_out_mfma<<<dim3(512),  blk, 0, stream>>>(Hb16, Wtup, out);
}